// Round 1
// baseline (2723.764 us; speedup 1.0000x reference)
//
#include <hip/hip_runtime.h>

#define N_USERS 100000
#define N_ITEMS 30000
#define NE      1000000
#define D       128

// ---------------- degree histograms (all 6 index arrays in one pass) ----------------
__global__ void k_degrees(const int* __restrict__ ou, const int* __restrict__ oi,
                          const int* __restrict__ su, const int* __restrict__ si,
                          const int* __restrict__ du, const int* __restrict__ di,
                          int* dOU, int* dOI, int* dSU, int* dSI, int* dDU, int* dDI) {
    int e = blockIdx.x * blockDim.x + threadIdx.x;
    if (e >= NE) return;
    atomicAdd(&dOU[ou[e]], 1);
    atomicAdd(&dOI[oi[e]], 1);
    atomicAdd(&dSU[su[e]], 1);
    atomicAdd(&dSI[si[e]], 1);
    atomicAdd(&dDU[du[e]], 1);
    atomicAdd(&dDI[di[e]], 1);
}

// ---------------- exclusive scan over m = n+1 values (f(i) = i<n ? deg[i] : 0) -------
// K1: per-block (1024 elems) local exclusive scan + block sums
__global__ void k_scan1(const int* __restrict__ deg, int n,
                        int* __restrict__ out, int* __restrict__ bsum) {
    __shared__ int lds[256];
    const int m = n + 1;
    const int t = threadIdx.x;
    const int idx0 = blockIdx.x * 1024 + t * 4;
    int v[4];
    int s = 0;
#pragma unroll
    for (int j = 0; j < 4; ++j) {
        int i = idx0 + j;
        int x = (i < n) ? deg[i] : 0;
        v[j] = s;
        s += x;
    }
    lds[t] = s;
    __syncthreads();
    int add;
    for (int off = 1; off < 256; off <<= 1) {
        add = (t >= off) ? lds[t - off] : 0;
        __syncthreads();
        lds[t] += add;
        __syncthreads();
    }
    const int incl = lds[t];
    const int excl = incl - s;
#pragma unroll
    for (int j = 0; j < 4; ++j) {
        int i = idx0 + j;
        if (i < m) out[i] = excl + v[j];
    }
    if (t == 255) bsum[blockIdx.x] = incl;
}

// K2: single-block exclusive scan of block sums (nb <= 256)
__global__ void k_scan2(int* bsum, int nb) {
    __shared__ int lds[256];
    const int t = threadIdx.x;
    const int x = (t < nb) ? bsum[t] : 0;
    lds[t] = x;
    __syncthreads();
    int add;
    for (int off = 1; off < 256; off <<= 1) {
        add = (t >= off) ? lds[t - off] : 0;
        __syncthreads();
        lds[t] += add;
        __syncthreads();
    }
    if (t < nb) bsum[t] = lds[t] - x;   // exclusive
}

// K3: add block offsets, init cursors
__global__ void k_scan3(int* __restrict__ out, const int* __restrict__ bsum,
                        int n, int* __restrict__ cursor) {
    int i = blockIdx.x * blockDim.x + threadIdx.x;
    if (i >= n + 1) return;
    int v = out[i] + bsum[i >> 10];
    out[i] = v;
    if (i < n) cursor[i] = v;
}

// ---------------- CSR fill: compute folded edge coefficients, scatter into rows ------
__global__ void k_fill(const int* __restrict__ ou, const int* __restrict__ oi,
                       const int* __restrict__ su, const int* __restrict__ si,
                       const int* __restrict__ du, const int* __restrict__ di,
                       const float* __restrict__ w,
                       const int* dOU, const int* dOI, const int* dSU,
                       const int* dSI, const int* dDU, const int* dDI,
                       int* cOU, int* cOI, int* cSU, int* cSI, int* cDU, int* cDI,
                       int* sOU, float* fOU, int* sOI, float* fOI,
                       int* sSU, float* fSU, int* sSI, float* fSI,
                       int* sDU, float* fDU, int* sDI, float* fDI) {
    int e = blockIdx.x * blockDim.x + threadIdx.x;
    if (e >= NE) return;
    {   // ori graph: symmetric coefficient, W_SELF = 1
        int u = ou[e], i = oi[e];
        float c = (1.0f / sqrtf((float)dOU[u])) * (1.0f / sqrtf((float)dOI[i]));
        int pu = atomicAdd(&cOU[u], 1); sOU[pu] = i; fOU[pu] = c;
        int pi = atomicAdd(&cOI[i], 1); sOI[pi] = u; fOI[pi] = c;
    }
    {   // seek graph: user side gets 0.5*w[e], item side gets 0.5 (W_SEEK folded in)
        int u = su[e], i = si[e];
        float b = (1.0f / sqrtf((float)dSU[u])) * (1.0f / sqrtf((float)dSI[i]));
        int pu = atomicAdd(&cSU[u], 1); sSU[pu] = i; fSU[pu] = 0.5f * w[e] * b;
        int pi = atomicAdd(&cSI[i], 1); sSI[pi] = u; fSI[pi] = 0.5f * b;
    }
    {   // dn graph
        int u = du[e], i = di[e];
        float c = (1.0f / sqrtf((float)dDU[u])) * (1.0f / sqrtf((float)dDI[i]));
        int pu = atomicAdd(&cDU[u], 1); sDU[pu] = i; fDU[pu] = c;
        int pi = atomicAdd(&cDI[i], 1); sDI[pi] = u; fDI[pi] = c;
    }
}

// ---------------- fused conv: out[v] = sum_list1 c*x[s] + sum_list2 c*x[s] + base[v] --
// one wave (64 lanes) per destination node; lane covers 2 consecutive floats
__global__ void k_conv(const float* __restrict__ x,
                       const int* __restrict__ rs1, const int* __restrict__ src1,
                       const float* __restrict__ cof1,
                       const int* __restrict__ rs2, const int* __restrict__ src2,
                       const float* __restrict__ cof2,
                       const float* __restrict__ base,
                       float* __restrict__ out, int n) {
    const int wid  = (int)((blockIdx.x * blockDim.x + threadIdx.x) >> 6);
    const int lane = threadIdx.x & 63;
    if (wid >= n) return;
    float ax = 0.0f, ay = 0.0f;
    if (base) {
        const float2 b = *(const float2*)(base + (size_t)wid * D + lane * 2);
        ax = b.x; ay = b.y;
    }
    int j0 = rs1[wid], j1 = rs1[wid + 1];
    for (int j = j0; j < j1; ++j) {
        const int   s = src1[j];
        const float c = cof1[j];
        const float2 v = *(const float2*)(x + (size_t)s * D + lane * 2);
        ax = fmaf(c, v.x, ax);
        ay = fmaf(c, v.y, ay);
    }
    if (rs2) {
        j0 = rs2[wid]; j1 = rs2[wid + 1];
        for (int j = j0; j < j1; ++j) {
            const int   s = src2[j];
            const float c = cof2[j];
            const float2 v = *(const float2*)(x + (size_t)s * D + lane * 2);
            ax = fmaf(c, v.x, ax);
            ay = fmaf(c, v.y, ay);
        }
    }
    *(float2*)(out + (size_t)wid * D + lane * 2) = make_float2(ax, ay);
}

extern "C" void kernel_launch(void* const* d_in, const int* in_sizes, int n_in,
                              void* d_out, int out_size, void* d_ws, size_t ws_size,
                              hipStream_t stream) {
    const float* user_emb = (const float*)d_in[0];
    const float* item_emb = (const float*)d_in[1];
    const float* w_edge   = (const float*)d_in[2];
    const int* ou = (const int*)d_in[3];
    const int* oi = (const int*)d_in[4];
    const int* su = (const int*)d_in[5];
    const int* si = (const int*)d_in[6];
    const int* du = (const int*)d_in[7];
    const int* di = (const int*)d_in[8];
    float* out = (float*)d_out;

    const size_t SZ_U = (size_t)N_USERS * D;   // 12.8M floats
    const size_t SZ_I = (size_t)N_ITEMS * D;   //  3.84M floats

    // output slices: (hu, hi, hu, hi, h1u, h1i)
    float* o0 = out;
    float* o1 = o0 + SZ_U;
    float* o2 = o1 + SZ_I;
    float* o3 = o2 + SZ_U;
    float* o4 = o3 + SZ_I;
    float* o5 = o4 + SZ_U;

    // ---- workspace carve-out (~186 MB) ----
    char* ws = (char*)d_ws;
    size_t off = 0;
    auto alloc = [&](size_t bytes) -> void* {
        void* p = ws + off;
        off = (off + bytes + 255) & ~(size_t)255;
        return p;
    };

    size_t degBegin = off;
    int* dOU = (int*)alloc(N_USERS * 4);
    int* dOI = (int*)alloc(N_ITEMS * 4);
    int* dSU = (int*)alloc(N_USERS * 4);
    int* dSI = (int*)alloc(N_ITEMS * 4);
    int* dDU = (int*)alloc(N_USERS * 4);
    int* dDI = (int*)alloc(N_ITEMS * 4);
    size_t degEnd = off;

    int* rOU = (int*)alloc((N_USERS + 1) * 4);
    int* rOI = (int*)alloc((N_ITEMS + 1) * 4);
    int* rSU = (int*)alloc((N_USERS + 1) * 4);
    int* rSI = (int*)alloc((N_ITEMS + 1) * 4);
    int* rDU = (int*)alloc((N_USERS + 1) * 4);
    int* rDI = (int*)alloc((N_ITEMS + 1) * 4);

    int* cOU = (int*)alloc(N_USERS * 4);
    int* cOI = (int*)alloc(N_ITEMS * 4);
    int* cSU = (int*)alloc(N_USERS * 4);
    int* cSI = (int*)alloc(N_ITEMS * 4);
    int* cDU = (int*)alloc(N_USERS * 4);
    int* cDI = (int*)alloc(N_ITEMS * 4);

    int* bsum = (int*)alloc(256 * 4);

    int*   sOU = (int*)alloc((size_t)NE * 4);  float* fOU = (float*)alloc((size_t)NE * 4);
    int*   sOI = (int*)alloc((size_t)NE * 4);  float* fOI = (float*)alloc((size_t)NE * 4);
    int*   sSU = (int*)alloc((size_t)NE * 4);  float* fSU = (float*)alloc((size_t)NE * 4);
    int*   sSI = (int*)alloc((size_t)NE * 4);  float* fSI = (float*)alloc((size_t)NE * 4);
    int*   sDU = (int*)alloc((size_t)NE * 4);  float* fDU = (float*)alloc((size_t)NE * 4);
    int*   sDI = (int*)alloc((size_t)NE * 4);  float* fDI = (float*)alloc((size_t)NE * 4);

    float* fU  = (float*)alloc(SZ_U * 4);   // 0.5 * h_user_seek_f
    float* fI  = (float*)alloc(SZ_I * 4);   // 0.5 * h_item_seek_f
    float* wsU = (float*)alloc(SZ_U * 4);   // loop-2 ping-pong
    float* wsI = (float*)alloc(SZ_I * 4);

    // ---- phase 0: zero degree histograms ----
    hipMemsetAsync(ws + degBegin, 0, degEnd - degBegin, stream);

    // ---- phase 1: degrees ----
    {
        dim3 g((NE + 255) / 256), b(256);
        hipLaunchKernelGGL(k_degrees, g, b, 0, stream, ou, oi, su, si, du, di,
                           dOU, dOI, dSU, dSI, dDU, dDI);
    }

    // ---- phase 2: scans (row starts + cursors) ----
    auto scan = [&](int* deg, int n, int* rs, int* cur) {
        int nb = (n + 1 + 1023) / 1024;
        hipLaunchKernelGGL(k_scan1, dim3(nb), dim3(256), 0, stream, deg, n, rs, bsum);
        hipLaunchKernelGGL(k_scan2, dim3(1), dim3(256), 0, stream, bsum, nb);
        hipLaunchKernelGGL(k_scan3, dim3((n + 1 + 255) / 256), dim3(256), 0, stream, rs, bsum, n, cur);
    };
    scan(dOU, N_USERS, rOU, cOU);
    scan(dOI, N_ITEMS, rOI, cOI);
    scan(dSU, N_USERS, rSU, cSU);
    scan(dSI, N_ITEMS, rSI, cSI);
    scan(dDU, N_USERS, rDU, cDU);
    scan(dDI, N_ITEMS, rDI, cDI);

    // ---- phase 3: CSR fill with folded coefficients ----
    {
        dim3 g((NE + 255) / 256), b(256);
        hipLaunchKernelGGL(k_fill, g, b, 0, stream,
                           ou, oi, su, si, du, di, w_edge,
                           dOU, dOI, dSU, dSI, dDU, dDI,
                           cOU, cOI, cSU, cSI, cDU, cDI,
                           sOU, fOU, sOI, fOI, sSU, fSU, sSI, fSI, sDU, fDU, sDI, fDI);
    }

    auto conv = [&](const float* x,
                    const int* rs1, const int* s1, const float* c1,
                    const int* rs2, const int* s2, const float* c2,
                    const float* basep, float* outp, int n) {
        dim3 g((unsigned)((n + 3) / 4)), b(256);  // 4 waves/block, 1 wave/node
        hipLaunchKernelGGL(k_conv, g, b, 0, stream, x, rs1, s1, c1, rs2, s2, c2, basep, outp, n);
    };

    // ---- phase 4: loop 1 (3 layers), ping-pong through output slices ----
    // iter0: (user_emb,item_emb) -> (o0,o1)
    conv(item_emb, rOU, sOU, fOU, rSU, sSU, fSU, nullptr, o0, N_USERS);
    conv(user_emb, rOI, sOI, fOI, rSI, sSI, fSI, nullptr, o1, N_ITEMS);
    // iter1: (o0,o1) -> (o2,o3)
    conv(o1, rOU, sOU, fOU, rSU, sSU, fSU, nullptr, o2, N_USERS);
    conv(o0, rOI, sOI, fOI, rSI, sSI, fSI, nullptr, o3, N_ITEMS);
    // iter2: (o2,o3) -> (o0,o1)
    conv(o3, rOU, sOU, fOU, rSU, sSU, fSU, nullptr, o0, N_USERS);
    conv(o2, rOI, sOI, fOI, rSI, sSI, fSI, nullptr, o1, N_ITEMS);
    // duplicate final (hu,hi) into slices 2,3
    hipMemcpyAsync(o2, o0, SZ_U * 4, hipMemcpyDeviceToDevice, stream);
    hipMemcpyAsync(o3, o1, SZ_I * 4, hipMemcpyDeviceToDevice, stream);

    // ---- phase 5: constant seek terms from final (hu,hi); coefs already include 0.5 ----
    conv(o1, rSU, sSU, fSU, nullptr, nullptr, nullptr, nullptr, fU, N_USERS);
    conv(o0, rSI, sSI, fSI, nullptr, nullptr, nullptr, nullptr, fI, N_ITEMS);

    // ---- phase 6: loop 2 (3 layers), dn graph + constant base ----
    // iter0: (user_emb,item_emb) -> (wsU,wsI)
    conv(item_emb, rDU, sDU, fDU, nullptr, nullptr, nullptr, fU, wsU, N_USERS);
    conv(user_emb, rDI, sDI, fDI, nullptr, nullptr, nullptr, fI, wsI, N_ITEMS);
    // iter1: (wsU,wsI) -> (o4,o5)
    conv(wsI, rDU, sDU, fDU, nullptr, nullptr, nullptr, fU, o4, N_USERS);
    conv(wsU, rDI, sDI, fDI, nullptr, nullptr, nullptr, fI, o5, N_ITEMS);
    // iter2: (o4,o5) -> (wsU,wsI)
    conv(o5, rDU, sDU, fDU, nullptr, nullptr, nullptr, fU, wsU, N_USERS);
    conv(o4, rDI, sDI, fDI, nullptr, nullptr, nullptr, fI, wsI, N_ITEMS);
    // final (h1u,h1i) into slices 4,5
    hipMemcpyAsync(o4, wsU, SZ_U * 4, hipMemcpyDeviceToDevice, stream);
    hipMemcpyAsync(o5, wsI, SZ_I * 4, hipMemcpyDeviceToDevice, stream);
}

// Round 2
// 1879.523 us; speedup vs baseline: 1.4492x; 1.4492x over previous
//
#include <hip/hip_runtime.h>

#define N_USERS 100000
#define N_ITEMS 30000
#define NE      1000000
#define D       128

// ---------------- degree histograms (all 6 index arrays in one pass) ----------------
__global__ void k_degrees(const int* __restrict__ ou, const int* __restrict__ oi,
                          const int* __restrict__ su, const int* __restrict__ si,
                          const int* __restrict__ du, const int* __restrict__ di,
                          int* dOU, int* dOI, int* dSU, int* dSI, int* dDU, int* dDI) {
    int e = blockIdx.x * blockDim.x + threadIdx.x;
    if (e >= NE) return;
    atomicAdd(&dOU[ou[e]], 1);
    atomicAdd(&dOI[oi[e]], 1);
    atomicAdd(&dSU[su[e]], 1);
    atomicAdd(&dSI[si[e]], 1);
    atomicAdd(&dDU[du[e]], 1);
    atomicAdd(&dDI[di[e]], 1);
}

// ---------------- batched exclusive scans: 6 arrays via blockIdx.y ----------------
struct ScanArgs {
    const int* deg[6];
    int* rs[6];
    int* cur[6];
    int* bsum;     // [6*256]
    int n[6];
};

// K1: per-block (1024 elems) local exclusive scan + block sums
__global__ void k_scan1(ScanArgs a) {
    __shared__ int lds[256];
    const int ai = blockIdx.y;
    const int n = a.n[ai];
    const int m = n + 1;
    const int t = threadIdx.x;
    const int idx0 = blockIdx.x * 1024 + t * 4;
    const int* __restrict__ deg = a.deg[ai];
    int* __restrict__ out = a.rs[ai];
    int v[4];
    int s = 0;
#pragma unroll
    for (int j = 0; j < 4; ++j) {
        int i = idx0 + j;
        int x = (i < n) ? deg[i] : 0;
        v[j] = s;
        s += x;
    }
    lds[t] = s;
    __syncthreads();
    int add;
    for (int off = 1; off < 256; off <<= 1) {
        add = (t >= off) ? lds[t - off] : 0;
        __syncthreads();
        lds[t] += add;
        __syncthreads();
    }
    const int incl = lds[t];
    const int excl = incl - s;
#pragma unroll
    for (int j = 0; j < 4; ++j) {
        int i = idx0 + j;
        if (i < m) out[i] = excl + v[j];
    }
    if (t == 255) a.bsum[ai * 256 + blockIdx.x] = incl;
}

// K2: one block per array, exclusive scan of its 256 block sums
__global__ void k_scan2(int* bsum) {
    __shared__ int lds[256];
    const int t = threadIdx.x;
    int* b = bsum + blockIdx.x * 256;
    const int x = b[t];
    lds[t] = x;
    __syncthreads();
    int add;
    for (int off = 1; off < 256; off <<= 1) {
        add = (t >= off) ? lds[t - off] : 0;
        __syncthreads();
        lds[t] += add;
        __syncthreads();
    }
    b[t] = lds[t] - x;   // exclusive
}

// K3: add block offsets, init cursors
__global__ void k_scan3(ScanArgs a) {
    const int ai = blockIdx.y;
    const int n = a.n[ai];
    const int i = blockIdx.x * blockDim.x + threadIdx.x;
    if (i >= n + 1) return;
    int v = a.rs[ai][i] + a.bsum[ai * 256 + (i >> 10)];
    a.rs[ai][i] = v;
    if (i < n) a.cur[ai][i] = v;
}

// ---------------- CSR fill: folded edge coefficients, (src,coef) int2 scatter -------
__global__ void k_fill(const int* __restrict__ ou, const int* __restrict__ oi,
                       const int* __restrict__ su, const int* __restrict__ si,
                       const int* __restrict__ du, const int* __restrict__ di,
                       const float* __restrict__ w,
                       const int* dOU, const int* dOI, const int* dSU,
                       const int* dSI, const int* dDU, const int* dDI,
                       int* cOU, int* cOI, int* cSU, int* cSI, int* cDU, int* cDI,
                       int2* pOU, int2* pOI, int2* pSU, int2* pSI, int2* pDU, int2* pDI) {
    int e = blockIdx.x * blockDim.x + threadIdx.x;
    if (e >= NE) return;
    {   // ori graph: symmetric coefficient, W_SELF = 1
        int u = ou[e], i = oi[e];
        float c = (1.0f / sqrtf((float)dOU[u])) * (1.0f / sqrtf((float)dOI[i]));
        int pu = atomicAdd(&cOU[u], 1); pOU[pu] = make_int2(i, __float_as_int(c));
        int pi = atomicAdd(&cOI[i], 1); pOI[pi] = make_int2(u, __float_as_int(c));
    }
    {   // seek graph: user side gets 0.5*w[e], item side 0.5 (W_SEEK folded in)
        int u = su[e], i = si[e];
        float b = (1.0f / sqrtf((float)dSU[u])) * (1.0f / sqrtf((float)dSI[i]));
        int pu = atomicAdd(&cSU[u], 1); pSU[pu] = make_int2(i, __float_as_int(0.5f * w[e] * b));
        int pi = atomicAdd(&cSI[i], 1); pSI[pi] = make_int2(u, __float_as_int(0.5f * b));
    }
    {   // dn graph
        int u = du[e], i = di[e];
        float c = (1.0f / sqrtf((float)dDU[u])) * (1.0f / sqrtf((float)dDI[i]));
        int pu = atomicAdd(&cDU[u], 1); pDU[pu] = make_int2(i, __float_as_int(c));
        int pi = atomicAdd(&cDI[i], 1); pDI[pi] = make_int2(u, __float_as_int(c));
    }
}

// ---------------- fused conv ----------------
// half-wave (32 lanes) per destination node, float4 per lane (16B, full 512B row).
// Lane-parallel index prefetch: 32 lanes load 32 (src,coef) pairs coalesced, then
// broadcast one at a time via __shfl within the 32-lane group.
__global__ void k_conv(const float* __restrict__ x,
                       const int* __restrict__ rs1, const int2* __restrict__ p1,
                       const int* __restrict__ rs2, const int2* __restrict__ p2,
                       const float* __restrict__ base,
                       float* __restrict__ out, float* __restrict__ out2, int n) {
    const int hw   = (int)((blockIdx.x * blockDim.x + threadIdx.x) >> 5);
    const int lane = threadIdx.x & 31;
    if (hw >= n) return;
    float4 acc;
    if (base) {
        acc = *(const float4*)(base + (size_t)hw * D + lane * 4);
    } else {
        acc = make_float4(0.f, 0.f, 0.f, 0.f);
    }
    {
        const int j0 = rs1[hw], j1 = rs1[hw + 1];
        for (int jb = j0; jb < j1; jb += 32) {
            int2 mp = make_int2(0, 0);
            if (jb + lane < j1) mp = p1[jb + lane];
            const int cnt = min(32, j1 - jb);
            for (int t = 0; t < cnt; ++t) {
                const int   s = __shfl(mp.x, t, 32);
                const float c = __int_as_float(__shfl(mp.y, t, 32));
                const float4 v = *(const float4*)(x + (size_t)s * D + lane * 4);
                acc.x = fmaf(c, v.x, acc.x);
                acc.y = fmaf(c, v.y, acc.y);
                acc.z = fmaf(c, v.z, acc.z);
                acc.w = fmaf(c, v.w, acc.w);
            }
        }
    }
    if (rs2) {
        const int j0 = rs2[hw], j1 = rs2[hw + 1];
        for (int jb = j0; jb < j1; jb += 32) {
            int2 mp = make_int2(0, 0);
            if (jb + lane < j1) mp = p2[jb + lane];
            const int cnt = min(32, j1 - jb);
            for (int t = 0; t < cnt; ++t) {
                const int   s = __shfl(mp.x, t, 32);
                const float c = __int_as_float(__shfl(mp.y, t, 32));
                const float4 v = *(const float4*)(x + (size_t)s * D + lane * 4);
                acc.x = fmaf(c, v.x, acc.x);
                acc.y = fmaf(c, v.y, acc.y);
                acc.z = fmaf(c, v.z, acc.z);
                acc.w = fmaf(c, v.w, acc.w);
            }
        }
    }
    *(float4*)(out + (size_t)hw * D + lane * 4) = acc;
    if (out2) *(float4*)(out2 + (size_t)hw * D + lane * 4) = acc;
}

extern "C" void kernel_launch(void* const* d_in, const int* in_sizes, int n_in,
                              void* d_out, int out_size, void* d_ws, size_t ws_size,
                              hipStream_t stream) {
    const float* user_emb = (const float*)d_in[0];
    const float* item_emb = (const float*)d_in[1];
    const float* w_edge   = (const float*)d_in[2];
    const int* ou = (const int*)d_in[3];
    const int* oi = (const int*)d_in[4];
    const int* su = (const int*)d_in[5];
    const int* si = (const int*)d_in[6];
    const int* du = (const int*)d_in[7];
    const int* di = (const int*)d_in[8];
    float* out = (float*)d_out;

    const size_t SZ_U = (size_t)N_USERS * D;
    const size_t SZ_I = (size_t)N_ITEMS * D;

    // output slices: (hu, hi, hu, hi, h1u, h1i)
    float* o0 = out;
    float* o1 = o0 + SZ_U;
    float* o2 = o1 + SZ_I;
    float* o3 = o2 + SZ_U;
    float* o4 = o3 + SZ_I;
    float* o5 = o4 + SZ_U;

    // ---- workspace carve-out ----
    char* ws = (char*)d_ws;
    size_t off = 0;
    auto alloc = [&](size_t bytes) -> void* {
        void* p = ws + off;
        off = (off + bytes + 255) & ~(size_t)255;
        return p;
    };

    size_t degBegin = off;
    int* dOU = (int*)alloc(N_USERS * 4);
    int* dOI = (int*)alloc(N_ITEMS * 4);
    int* dSU = (int*)alloc(N_USERS * 4);
    int* dSI = (int*)alloc(N_ITEMS * 4);
    int* dDU = (int*)alloc(N_USERS * 4);
    int* dDI = (int*)alloc(N_ITEMS * 4);
    size_t degEnd = off;

    int* rOU = (int*)alloc((N_USERS + 1) * 4);
    int* rOI = (int*)alloc((N_ITEMS + 1) * 4);
    int* rSU = (int*)alloc((N_USERS + 1) * 4);
    int* rSI = (int*)alloc((N_ITEMS + 1) * 4);
    int* rDU = (int*)alloc((N_USERS + 1) * 4);
    int* rDI = (int*)alloc((N_ITEMS + 1) * 4);

    int* cOU = (int*)alloc(N_USERS * 4);
    int* cOI = (int*)alloc(N_ITEMS * 4);
    int* cSU = (int*)alloc(N_USERS * 4);
    int* cSI = (int*)alloc(N_ITEMS * 4);
    int* cDU = (int*)alloc(N_USERS * 4);
    int* cDI = (int*)alloc(N_ITEMS * 4);

    int* bsum = (int*)alloc(6 * 256 * 4);

    int2* pOU = (int2*)alloc((size_t)NE * 8);
    int2* pOI = (int2*)alloc((size_t)NE * 8);
    int2* pSU = (int2*)alloc((size_t)NE * 8);
    int2* pSI = (int2*)alloc((size_t)NE * 8);
    int2* pDU = (int2*)alloc((size_t)NE * 8);
    int2* pDI = (int2*)alloc((size_t)NE * 8);

    float* fU  = (float*)alloc(SZ_U * 4);   // 0.5 * h_user_seek_f
    float* fI  = (float*)alloc(SZ_I * 4);   // 0.5 * h_item_seek_f
    float* wsU = (float*)alloc(SZ_U * 4);   // ping-pong middles
    float* wsI = (float*)alloc(SZ_I * 4);

    // ---- phase 0: zero degree histograms ----
    hipMemsetAsync(ws + degBegin, 0, degEnd - degBegin, stream);

    // ---- phase 1: degrees ----
    hipLaunchKernelGGL(k_degrees, dim3((NE + 255) / 256), dim3(256), 0, stream,
                       ou, oi, su, si, du, di, dOU, dOI, dSU, dSI, dDU, dDI);

    // ---- phase 2: batched scans ----
    ScanArgs sa;
    sa.deg[0] = dOU; sa.rs[0] = rOU; sa.cur[0] = cOU; sa.n[0] = N_USERS;
    sa.deg[1] = dOI; sa.rs[1] = rOI; sa.cur[1] = cOI; sa.n[1] = N_ITEMS;
    sa.deg[2] = dSU; sa.rs[2] = rSU; sa.cur[2] = cSU; sa.n[2] = N_USERS;
    sa.deg[3] = dSI; sa.rs[3] = rSI; sa.cur[3] = cSI; sa.n[3] = N_ITEMS;
    sa.deg[4] = dDU; sa.rs[4] = rDU; sa.cur[4] = cDU; sa.n[4] = N_USERS;
    sa.deg[5] = dDI; sa.rs[5] = rDI; sa.cur[5] = cDI; sa.n[5] = N_ITEMS;
    sa.bsum = bsum;
    {
        const int nb1 = (N_USERS + 1 + 1023) / 1024;                 // 98
        hipLaunchKernelGGL(k_scan1, dim3(nb1, 6), dim3(256), 0, stream, sa);
        hipLaunchKernelGGL(k_scan2, dim3(6), dim3(256), 0, stream, bsum);
        const int nb3 = (N_USERS + 1 + 255) / 256;                   // 391
        hipLaunchKernelGGL(k_scan3, dim3(nb3, 6), dim3(256), 0, stream, sa);
    }

    // ---- phase 3: CSR fill ----
    hipLaunchKernelGGL(k_fill, dim3((NE + 255) / 256), dim3(256), 0, stream,
                       ou, oi, su, si, du, di, w_edge,
                       dOU, dOI, dSU, dSI, dDU, dDI,
                       cOU, cOI, cSU, cSI, cDU, cDI,
                       pOU, pOI, pSU, pSI, pDU, pDI);

    auto conv = [&](const float* x,
                    const int* rs1, const int2* l1,
                    const int* rs2, const int2* l2,
                    const float* basep, float* outp, float* outp2, int n) {
        dim3 g((unsigned)((n + 7) / 8)), b(256);  // 8 half-waves per block
        hipLaunchKernelGGL(k_conv, g, b, 0, stream, x, rs1, l1, rs2, l2,
                           basep, outp, outp2, n);
    };

    // ---- phase 4: loop 1 (3 layers) ----
    // iter0: (user_emb,item_emb) -> (o0,o1)
    conv(item_emb, rOU, pOU, rSU, pSU, nullptr, o0, nullptr, N_USERS);
    conv(user_emb, rOI, pOI, rSI, pSI, nullptr, o1, nullptr, N_ITEMS);
    // iter1: (o0,o1) -> (wsU,wsI)
    conv(o1, rOU, pOU, rSU, pSU, nullptr, wsU, nullptr, N_USERS);
    conv(o0, rOI, pOI, rSI, pSI, nullptr, wsI, nullptr, N_ITEMS);
    // iter2: (wsU,wsI) -> (o0,o1), dual-store duplicates into (o2,o3)
    conv(wsI, rOU, pOU, rSU, pSU, nullptr, o0, o2, N_USERS);
    conv(wsU, rOI, pOI, rSI, pSI, nullptr, o1, o3, N_ITEMS);

    // ---- phase 5: constant seek terms from final (hu=o0, hi=o1); coefs include 0.5 --
    conv(o1, rSU, pSU, nullptr, nullptr, nullptr, fU, nullptr, N_USERS);
    conv(o0, rSI, pSI, nullptr, nullptr, nullptr, fI, nullptr, N_ITEMS);

    // ---- phase 6: loop 2 (3 layers), dn graph + constant base ----
    // iter0: (user_emb,item_emb) -> (o4,o5)
    conv(item_emb, rDU, pDU, nullptr, nullptr, fU, o4, nullptr, N_USERS);
    conv(user_emb, rDI, pDI, nullptr, nullptr, fI, o5, nullptr, N_ITEMS);
    // iter1: (o4,o5) -> (wsU,wsI)
    conv(o5, rDU, pDU, nullptr, nullptr, fU, wsU, nullptr, N_USERS);
    conv(o4, rDI, pDI, nullptr, nullptr, fI, wsI, nullptr, N_ITEMS);
    // iter2: (wsU,wsI) -> (o4,o5)
    conv(wsI, rDU, pDU, nullptr, nullptr, fU, o4, nullptr, N_USERS);
    conv(wsU, rDI, pDI, nullptr, nullptr, fI, o5, nullptr, N_ITEMS);
}

// Round 3
// 1807.000 us; speedup vs baseline: 1.5073x; 1.0401x over previous
//
#include <hip/hip_runtime.h>

#define N_USERS 100000
#define N_ITEMS 30000
#define NE      1000000
#define D       128

__device__ __forceinline__ unsigned f2bf(float f) {
    unsigned u = __float_as_uint(f);
    return (u + 0x7fffu + ((u >> 16) & 1u)) >> 16;   // RNE, no NaN expected
}

// ---------------- degree histograms (all 6 index arrays in one pass) ----------------
__global__ void k_degrees(const int* __restrict__ ou, const int* __restrict__ oi,
                          const int* __restrict__ su, const int* __restrict__ si,
                          const int* __restrict__ du, const int* __restrict__ di,
                          int* dOU, int* dOI, int* dSU, int* dSI, int* dDU, int* dDI) {
    int e = blockIdx.x * blockDim.x + threadIdx.x;
    if (e >= NE) return;
    atomicAdd(&dOU[ou[e]], 1);
    atomicAdd(&dOI[oi[e]], 1);
    atomicAdd(&dSU[su[e]], 1);
    atomicAdd(&dSI[si[e]], 1);
    atomicAdd(&dDU[du[e]], 1);
    atomicAdd(&dDI[di[e]], 1);
}

// ---------------- batched exclusive scans: 6 arrays via blockIdx.y ----------------
struct ScanArgs {
    const int* deg[6];
    int* rs[6];
    int* cur[6];
    int* bsum;     // [6*256]
    int n[6];
};

__global__ void k_scan1(ScanArgs a) {
    __shared__ int lds[256];
    const int ai = blockIdx.y;
    const int n = a.n[ai];
    const int m = n + 1;
    const int t = threadIdx.x;
    const int idx0 = blockIdx.x * 1024 + t * 4;
    const int* __restrict__ deg = a.deg[ai];
    int* __restrict__ out = a.rs[ai];
    int v[4];
    int s = 0;
#pragma unroll
    for (int j = 0; j < 4; ++j) {
        int i = idx0 + j;
        int x = (i < n) ? deg[i] : 0;
        v[j] = s;
        s += x;
    }
    lds[t] = s;
    __syncthreads();
    int add;
    for (int off = 1; off < 256; off <<= 1) {
        add = (t >= off) ? lds[t - off] : 0;
        __syncthreads();
        lds[t] += add;
        __syncthreads();
    }
    const int incl = lds[t];
    const int excl = incl - s;
#pragma unroll
    for (int j = 0; j < 4; ++j) {
        int i = idx0 + j;
        if (i < m) out[i] = excl + v[j];
    }
    if (t == 255) a.bsum[ai * 256 + blockIdx.x] = incl;
}

__global__ void k_scan2(int* bsum) {
    __shared__ int lds[256];
    const int t = threadIdx.x;
    int* b = bsum + blockIdx.x * 256;
    const int x = b[t];
    lds[t] = x;
    __syncthreads();
    int add;
    for (int off = 1; off < 256; off <<= 1) {
        add = (t >= off) ? lds[t - off] : 0;
        __syncthreads();
        lds[t] += add;
        __syncthreads();
    }
    b[t] = lds[t] - x;   // exclusive
}

__global__ void k_scan3(ScanArgs a) {
    const int ai = blockIdx.y;
    const int n = a.n[ai];
    const int i = blockIdx.x * blockDim.x + threadIdx.x;
    if (i >= n + 1) return;
    int v = a.rs[ai][i] + a.bsum[ai * 256 + (i >> 10)];
    a.rs[ai][i] = v;
    if (i < n) a.cur[ai][i] = v;
}

// ---------------- CSR fill: folded edge coefficients, (src,coef) int2 scatter -------
__global__ void k_fill(const int* __restrict__ ou, const int* __restrict__ oi,
                       const int* __restrict__ su, const int* __restrict__ si,
                       const int* __restrict__ du, const int* __restrict__ di,
                       const float* __restrict__ w,
                       const int* dOU, const int* dOI, const int* dSU,
                       const int* dSI, const int* dDU, const int* dDI,
                       int* cOU, int* cOI, int* cSU, int* cSI, int* cDU, int* cDI,
                       int2* pOU, int2* pOI, int2* pSU, int2* pSI, int2* pDU, int2* pDI) {
    int e = blockIdx.x * blockDim.x + threadIdx.x;
    if (e >= NE) return;
    {   // ori graph: symmetric coefficient, W_SELF = 1
        int u = ou[e], i = oi[e];
        float c = (1.0f / sqrtf((float)dOU[u])) * (1.0f / sqrtf((float)dOI[i]));
        int pu = atomicAdd(&cOU[u], 1); pOU[pu] = make_int2(i, __float_as_int(c));
        int pi = atomicAdd(&cOI[i], 1); pOI[pi] = make_int2(u, __float_as_int(c));
    }
    {   // seek graph: user side gets 0.5*w[e], item side 0.5 (W_SEEK folded in)
        int u = su[e], i = si[e];
        float b = (1.0f / sqrtf((float)dSU[u])) * (1.0f / sqrtf((float)dSI[i]));
        int pu = atomicAdd(&cSU[u], 1); pSU[pu] = make_int2(i, __float_as_int(0.5f * w[e] * b));
        int pi = atomicAdd(&cSI[i], 1); pSI[pi] = make_int2(u, __float_as_int(0.5f * b));
    }
    {   // dn graph
        int u = du[e], i = di[e];
        float c = (1.0f / sqrtf((float)dDU[u])) * (1.0f / sqrtf((float)dDI[i]));
        int pu = atomicAdd(&cDU[u], 1); pDU[pu] = make_int2(i, __float_as_int(c));
        int pi = atomicAdd(&cDI[i], 1); pDI[pi] = make_int2(u, __float_as_int(c));
    }
}

// ---------------- f32 -> bf16 convert (4 floats / thread) ----------------
__global__ void k_tobf16(const float* __restrict__ in, ushort* __restrict__ out, int n4) {
    int i = blockIdx.x * blockDim.x + threadIdx.x;
    if (i >= n4) return;
    float4 v = ((const float4*)in)[i];
    ((uint2*)out)[i] = make_uint2((f2bf(v.y) << 16) | f2bf(v.x),
                                  (f2bf(v.w) << 16) | f2bf(v.z));
}

// ---------------- fused conv ----------------
// full wave (64 lanes) per destination row; lane covers 2 consecutive bf16 elems (4B).
// Accumulate f32; optional f32 outputs (x2) and/or bf16 output; optional bf16 base.
__global__ void k_conv(const ushort* __restrict__ x,
                       const int* __restrict__ rs1, const int2* __restrict__ p1,
                       const int* __restrict__ rs2, const int2* __restrict__ p2,
                       const ushort* __restrict__ base,
                       float* __restrict__ outf, float* __restrict__ outf2,
                       ushort* __restrict__ outb, int n) {
    const int row  = (int)((blockIdx.x * blockDim.x + threadIdx.x) >> 6);
    const int lane = threadIdx.x & 63;
    if (row >= n) return;
    const size_t roff = (size_t)row * D + lane * 2;
    float ax = 0.f, ay = 0.f;
    if (base) {
        const unsigned b = *(const unsigned*)(base + roff);
        ax = __uint_as_float(b << 16);
        ay = __uint_as_float(b & 0xffff0000u);
    }
    {
        const int j0 = rs1[row], j1 = rs1[row + 1];
        for (int jb = j0; jb < j1; jb += 64) {
            int2 mp = make_int2(0, 0);
            if (jb + lane < j1) mp = p1[jb + lane];
            const int cnt = min(64, j1 - jb);
            for (int t = 0; t < cnt; ++t) {
                const int   s = __shfl(mp.x, t, 64);
                const float c = __int_as_float(__shfl(mp.y, t, 64));
                const unsigned v = *(const unsigned*)(x + (size_t)s * D + lane * 2);
                ax = fmaf(c, __uint_as_float(v << 16), ax);
                ay = fmaf(c, __uint_as_float(v & 0xffff0000u), ay);
            }
        }
    }
    if (rs2) {
        const int j0 = rs2[row], j1 = rs2[row + 1];
        for (int jb = j0; jb < j1; jb += 64) {
            int2 mp = make_int2(0, 0);
            if (jb + lane < j1) mp = p2[jb + lane];
            const int cnt = min(64, j1 - jb);
            for (int t = 0; t < cnt; ++t) {
                const int   s = __shfl(mp.x, t, 64);
                const float c = __int_as_float(__shfl(mp.y, t, 64));
                const unsigned v = *(const unsigned*)(x + (size_t)s * D + lane * 2);
                ax = fmaf(c, __uint_as_float(v << 16), ax);
                ay = fmaf(c, __uint_as_float(v & 0xffff0000u), ay);
            }
        }
    }
    if (outf)  *(float2*)(outf  + roff) = make_float2(ax, ay);
    if (outf2) *(float2*)(outf2 + roff) = make_float2(ax, ay);
    if (outb)  *(unsigned*)(outb + roff) = (f2bf(ay) << 16) | f2bf(ax);
}

extern "C" void kernel_launch(void* const* d_in, const int* in_sizes, int n_in,
                              void* d_out, int out_size, void* d_ws, size_t ws_size,
                              hipStream_t stream) {
    const float* user_emb = (const float*)d_in[0];
    const float* item_emb = (const float*)d_in[1];
    const float* w_edge   = (const float*)d_in[2];
    const int* ou = (const int*)d_in[3];
    const int* oi = (const int*)d_in[4];
    const int* su = (const int*)d_in[5];
    const int* si = (const int*)d_in[6];
    const int* du = (const int*)d_in[7];
    const int* di = (const int*)d_in[8];
    float* out = (float*)d_out;

    const size_t SZ_U = (size_t)N_USERS * D;
    const size_t SZ_I = (size_t)N_ITEMS * D;

    // output slices: (hu, hi, hu, hi, h1u, h1i)
    float* o0 = out;
    float* o1 = o0 + SZ_U;
    float* o2 = o1 + SZ_I;
    float* o3 = o2 + SZ_U;
    float* o4 = o3 + SZ_I;
    float* o5 = o4 + SZ_U;

    // bf16 intermediates live in the o4/o5 slices (dead until loop-2 iter2):
    // o4 region (SZ_U floats) holds tU0+tU1 (2*SZ_U ushorts); o5 holds tI0+tI1.
    ushort* tU0 = (ushort*)o4;  ushort* tU1 = tU0 + SZ_U;
    ushort* tI0 = (ushort*)o5;  ushort* tI1 = tI0 + SZ_I;

    // ---- workspace carve-out (~120 MB) ----
    char* ws = (char*)d_ws;
    size_t off = 0;
    auto alloc = [&](size_t bytes) -> void* {
        void* p = ws + off;
        off = (off + bytes + 255) & ~(size_t)255;
        return p;
    };

    size_t degBegin = off;
    int* dOU = (int*)alloc(N_USERS * 4);
    int* dOI = (int*)alloc(N_ITEMS * 4);
    int* dSU = (int*)alloc(N_USERS * 4);
    int* dSI = (int*)alloc(N_ITEMS * 4);
    int* dDU = (int*)alloc(N_USERS * 4);
    int* dDI = (int*)alloc(N_ITEMS * 4);
    size_t degEnd = off;

    int* rOU = (int*)alloc((N_USERS + 1) * 4);
    int* rOI = (int*)alloc((N_ITEMS + 1) * 4);
    int* rSU = (int*)alloc((N_USERS + 1) * 4);
    int* rSI = (int*)alloc((N_ITEMS + 1) * 4);
    int* rDU = (int*)alloc((N_USERS + 1) * 4);
    int* rDI = (int*)alloc((N_ITEMS + 1) * 4);

    int* cOU = (int*)alloc(N_USERS * 4);
    int* cOI = (int*)alloc(N_ITEMS * 4);
    int* cSU = (int*)alloc(N_USERS * 4);
    int* cSI = (int*)alloc(N_ITEMS * 4);
    int* cDU = (int*)alloc(N_USERS * 4);
    int* cDI = (int*)alloc(N_ITEMS * 4);

    int* bsum = (int*)alloc(6 * 256 * 4);

    int2* pOU = (int2*)alloc((size_t)NE * 8);
    int2* pOI = (int2*)alloc((size_t)NE * 8);
    int2* pSU = (int2*)alloc((size_t)NE * 8);
    int2* pSI = (int2*)alloc((size_t)NE * 8);
    int2* pDU = (int2*)alloc((size_t)NE * 8);
    int2* pDI = (int2*)alloc((size_t)NE * 8);

    ushort* ebU = (ushort*)alloc(SZ_U * 2);   // bf16 copy of user_emb (reused loop2 iter1)
    ushort* ebI = (ushort*)alloc(SZ_I * 2);   // bf16 copy of item_emb (reused loop2 iter1)
    ushort* fUb = (ushort*)alloc(SZ_U * 2);   // bf16 0.5*h_user_seek_f
    ushort* fIb = (ushort*)alloc(SZ_I * 2);   // bf16 0.5*h_item_seek_f

    // ---- phase 0: zero degree histograms; convert embeddings to bf16 ----
    hipMemsetAsync(ws + degBegin, 0, degEnd - degBegin, stream);
    hipLaunchKernelGGL(k_tobf16, dim3((unsigned)(SZ_U / 4 + 255) / 256), dim3(256), 0, stream,
                       user_emb, ebU, (int)(SZ_U / 4));
    hipLaunchKernelGGL(k_tobf16, dim3((unsigned)(SZ_I / 4 + 255) / 256), dim3(256), 0, stream,
                       item_emb, ebI, (int)(SZ_I / 4));

    // ---- phase 1: degrees ----
    hipLaunchKernelGGL(k_degrees, dim3((NE + 255) / 256), dim3(256), 0, stream,
                       ou, oi, su, si, du, di, dOU, dOI, dSU, dSI, dDU, dDI);

    // ---- phase 2: batched scans ----
    ScanArgs sa;
    sa.deg[0] = dOU; sa.rs[0] = rOU; sa.cur[0] = cOU; sa.n[0] = N_USERS;
    sa.deg[1] = dOI; sa.rs[1] = rOI; sa.cur[1] = cOI; sa.n[1] = N_ITEMS;
    sa.deg[2] = dSU; sa.rs[2] = rSU; sa.cur[2] = cSU; sa.n[2] = N_USERS;
    sa.deg[3] = dSI; sa.rs[3] = rSI; sa.cur[3] = cSI; sa.n[3] = N_ITEMS;
    sa.deg[4] = dDU; sa.rs[4] = rDU; sa.cur[4] = cDU; sa.n[4] = N_USERS;
    sa.deg[5] = dDI; sa.rs[5] = rDI; sa.cur[5] = cDI; sa.n[5] = N_ITEMS;
    sa.bsum = bsum;
    {
        const int nb1 = (N_USERS + 1 + 1023) / 1024;                 // 98
        hipLaunchKernelGGL(k_scan1, dim3(nb1, 6), dim3(256), 0, stream, sa);
        hipLaunchKernelGGL(k_scan2, dim3(6), dim3(256), 0, stream, bsum);
        const int nb3 = (N_USERS + 1 + 255) / 256;                   // 391
        hipLaunchKernelGGL(k_scan3, dim3(nb3, 6), dim3(256), 0, stream, sa);
    }

    // ---- phase 3: CSR fill ----
    hipLaunchKernelGGL(k_fill, dim3((NE + 255) / 256), dim3(256), 0, stream,
                       ou, oi, su, si, du, di, w_edge,
                       dOU, dOI, dSU, dSI, dDU, dDI,
                       cOU, cOI, cSU, cSI, cDU, cDI,
                       pOU, pOI, pSU, pSI, pDU, pDI);

    auto conv = [&](const ushort* x,
                    const int* rs1, const int2* l1,
                    const int* rs2, const int2* l2,
                    const ushort* basep, float* outf, float* outf2, ushort* outb, int n) {
        dim3 g((unsigned)((n + 3) / 4)), b(256);  // 4 waves/block, 1 wave/row
        hipLaunchKernelGGL(k_conv, g, b, 0, stream, x, rs1, l1, rs2, l2,
                           basep, outf, outf2, outb, n);
    };

    // ---- phase 4: loop 1 (3 layers), bf16 intermediates ----
    // iter0: (ebU,ebI) -> (tU0,tI0)
    conv(ebI, rOU, pOU, rSU, pSU, nullptr, nullptr, nullptr, tU0, N_USERS);
    conv(ebU, rOI, pOI, rSI, pSI, nullptr, nullptr, nullptr, tI0, N_ITEMS);
    // iter1: (tU0,tI0) -> (tU1,tI1)
    conv(tI0, rOU, pOU, rSU, pSU, nullptr, nullptr, nullptr, tU1, N_USERS);
    conv(tU0, rOI, pOI, rSI, pSI, nullptr, nullptr, nullptr, tI1, N_ITEMS);
    // iter2: (tU1,tI1) -> f32 (o0,o1) + dup (o2,o3) + bf16 finals (tU0,tI0 reused)
    conv(tI1, rOU, pOU, rSU, pSU, nullptr, o0, o2, tU0, N_USERS);
    conv(tU1, rOI, pOI, rSI, pSI, nullptr, o1, o3, tI0, N_ITEMS);

    // ---- phase 5: constant seek terms from bf16 finals; coefs include the 0.5 ----
    conv(tI0, rSU, pSU, nullptr, nullptr, nullptr, nullptr, nullptr, fUb, N_USERS);
    conv(tU0, rSI, pSI, nullptr, nullptr, nullptr, nullptr, nullptr, fIb, N_ITEMS);

    // ---- phase 6: loop 2 (3 layers), dn graph + constant bf16 base ----
    // iter0: (ebU,ebI) -> (tU1,tI1)
    conv(ebI, rDU, pDU, nullptr, nullptr, fUb, nullptr, nullptr, tU1, N_USERS);
    conv(ebU, rDI, pDI, nullptr, nullptr, fIb, nullptr, nullptr, tI1, N_ITEMS);
    // iter1: (tU1,tI1) -> (ebU,ebI reused as scratch)
    conv(tI1, rDU, pDU, nullptr, nullptr, fUb, nullptr, nullptr, ebU, N_USERS);
    conv(tU1, rDI, pDI, nullptr, nullptr, fIb, nullptr, nullptr, ebI, N_ITEMS);
    // iter2: (ebU,ebI) -> f32 (o4,o5)   [overwrites the t-buffers: all dead now]
    conv(ebI, rDU, pDU, nullptr, nullptr, fUb, o4, nullptr, nullptr, N_USERS);
    conv(ebU, rDI, pDI, nullptr, nullptr, fIb, o5, nullptr, nullptr, N_ITEMS);
}

// Round 4
// 1405.385 us; speedup vs baseline: 1.9381x; 1.2858x over previous
//
#include <hip/hip_runtime.h>

#define N_USERS 100000
#define N_ITEMS 30000
#define NE      1000000
#define D       128

__device__ __forceinline__ unsigned f2bf(float f) {
    unsigned u = __float_as_uint(f);
    return (u + 0x7fffu + ((u >> 16) & 1u)) >> 16;   // RNE, no NaN expected
}
__device__ __forceinline__ float bflo(unsigned v) { return __uint_as_float(v << 16); }
__device__ __forceinline__ float bfhi(unsigned v) { return __uint_as_float(v & 0xffff0000u); }

// ---------------- degree histograms (all 6 index arrays in one pass) ----------------
__global__ void k_degrees(const int* __restrict__ ou, const int* __restrict__ oi,
                          const int* __restrict__ su, const int* __restrict__ si,
                          const int* __restrict__ du, const int* __restrict__ di,
                          int* dOU, int* dOI, int* dSU, int* dSI, int* dDU, int* dDI) {
    int e = blockIdx.x * blockDim.x + threadIdx.x;
    if (e >= NE) return;
    atomicAdd(&dOU[ou[e]], 1);
    atomicAdd(&dOI[oi[e]], 1);
    atomicAdd(&dSU[su[e]], 1);
    atomicAdd(&dSI[si[e]], 1);
    atomicAdd(&dDU[du[e]], 1);
    atomicAdd(&dDI[di[e]], 1);
}

// ---------------- batched exclusive scans: 6 arrays via blockIdx.y ----------------
struct ScanArgs {
    const int* deg[6];
    int* rs[6];
    int* cur[6];
    int* bsum;     // [6*256]
    int n[6];
};

__global__ void k_scan1(ScanArgs a) {
    __shared__ int lds[256];
    const int ai = blockIdx.y;
    const int n = a.n[ai];
    const int m = n + 1;
    const int t = threadIdx.x;
    const int idx0 = blockIdx.x * 1024 + t * 4;
    const int* __restrict__ deg = a.deg[ai];
    int* __restrict__ out = a.rs[ai];
    int v[4];
    int s = 0;
#pragma unroll
    for (int j = 0; j < 4; ++j) {
        int i = idx0 + j;
        int x = (i < n) ? deg[i] : 0;
        v[j] = s;
        s += x;
    }
    lds[t] = s;
    __syncthreads();
    int add;
    for (int off = 1; off < 256; off <<= 1) {
        add = (t >= off) ? lds[t - off] : 0;
        __syncthreads();
        lds[t] += add;
        __syncthreads();
    }
    const int incl = lds[t];
    const int excl = incl - s;
#pragma unroll
    for (int j = 0; j < 4; ++j) {
        int i = idx0 + j;
        if (i < m) out[i] = excl + v[j];
    }
    if (t == 255) a.bsum[ai * 256 + blockIdx.x] = incl;
}

__global__ void k_scan2(int* bsum) {
    __shared__ int lds[256];
    const int t = threadIdx.x;
    int* b = bsum + blockIdx.x * 256;
    const int x = b[t];
    lds[t] = x;
    __syncthreads();
    int add;
    for (int off = 1; off < 256; off <<= 1) {
        add = (t >= off) ? lds[t - off] : 0;
        __syncthreads();
        lds[t] += add;
        __syncthreads();
    }
    b[t] = lds[t] - x;   // exclusive
}

__global__ void k_scan3(ScanArgs a) {
    const int ai = blockIdx.y;
    const int n = a.n[ai];
    const int i = blockIdx.x * blockDim.x + threadIdx.x;
    if (i >= n + 1) return;
    int v = a.rs[ai][i] + a.bsum[ai * 256 + (i >> 10)];
    a.rs[ai][i] = v;
    if (i < n) a.cur[ai][i] = v;
}

// ---------------- CSR fill: folded edge coefficients, (src,coef) int2 scatter -------
__global__ void k_fill(const int* __restrict__ ou, const int* __restrict__ oi,
                       const int* __restrict__ su, const int* __restrict__ si,
                       const int* __restrict__ du, const int* __restrict__ di,
                       const float* __restrict__ w,
                       const int* dOU, const int* dOI, const int* dSU,
                       const int* dSI, const int* dDU, const int* dDI,
                       int* cOU, int* cOI, int* cSU, int* cSI, int* cDU, int* cDI,
                       int2* pOU, int2* pOI, int2* pSU, int2* pSI, int2* pDU, int2* pDI) {
    int e = blockIdx.x * blockDim.x + threadIdx.x;
    if (e >= NE) return;
    {   // ori graph: symmetric coefficient, W_SELF = 1
        int u = ou[e], i = oi[e];
        float c = (1.0f / sqrtf((float)dOU[u])) * (1.0f / sqrtf((float)dOI[i]));
        int pu = atomicAdd(&cOU[u], 1); pOU[pu] = make_int2(i, __float_as_int(c));
        int pi = atomicAdd(&cOI[i], 1); pOI[pi] = make_int2(u, __float_as_int(c));
    }
    {   // seek graph: user side gets 0.5*w[e], item side 0.5 (W_SEEK folded in)
        int u = su[e], i = si[e];
        float b = (1.0f / sqrtf((float)dSU[u])) * (1.0f / sqrtf((float)dSI[i]));
        int pu = atomicAdd(&cSU[u], 1); pSU[pu] = make_int2(i, __float_as_int(0.5f * w[e] * b));
        int pi = atomicAdd(&cSI[i], 1); pSI[pi] = make_int2(u, __float_as_int(0.5f * b));
    }
    {   // dn graph
        int u = du[e], i = di[e];
        float c = (1.0f / sqrtf((float)dDU[u])) * (1.0f / sqrtf((float)dDI[i]));
        int pu = atomicAdd(&cDU[u], 1); pDU[pu] = make_int2(i, __float_as_int(c));
        int pi = atomicAdd(&cDI[i], 1); pDI[pi] = make_int2(u, __float_as_int(c));
    }
}

// ---------------- f32 -> bf16 convert (4 floats / thread) ----------------
__global__ void k_tobf16(const float* __restrict__ in, ushort* __restrict__ out, int n4) {
    int i = blockIdx.x * blockDim.x + threadIdx.x;
    if (i >= n4) return;
    float4 v = ((const float4*)in)[i];
    ((uint2*)out)[i] = make_uint2((f2bf(v.y) << 16) | f2bf(v.x),
                                  (f2bf(v.w) << 16) | f2bf(v.z));
}

// ---------------- fused dual-side conv ----------------
// full wave (64 lanes) per destination row; lane covers 2 consecutive bf16 elems.
// Inner loop unrolled x4: 4 independent row-gathers in flight before FMAs consume.
struct ConvSide {
    const ushort* x;
    const int*  rs1; const int2* p1;
    const int*  rs2; const int2* p2;
    const ushort* base;
    float*  outf; float* outf2;
    ushort* outb;
    int n;
};

__device__ __forceinline__ void accum_list(const ushort* __restrict__ x,
                                           const int* __restrict__ rs,
                                           const int2* __restrict__ p,
                                           int row, int lane,
                                           float& ax, float& ay) {
    const int j0 = rs[row], j1 = rs[row + 1];
    for (int jb = j0; jb < j1; jb += 64) {
        int2 mp = make_int2(0, 0);
        if (jb + lane < j1) mp = p[jb + lane];
        const int cnt = min(64, j1 - jb);
        int t = 0;
        for (; t + 4 <= cnt; t += 4) {
            const int   s0 = __shfl(mp.x, t,     64);
            const int   s1 = __shfl(mp.x, t + 1, 64);
            const int   s2 = __shfl(mp.x, t + 2, 64);
            const int   s3 = __shfl(mp.x, t + 3, 64);
            const float c0 = __int_as_float(__shfl(mp.y, t,     64));
            const float c1 = __int_as_float(__shfl(mp.y, t + 1, 64));
            const float c2 = __int_as_float(__shfl(mp.y, t + 2, 64));
            const float c3 = __int_as_float(__shfl(mp.y, t + 3, 64));
            const unsigned v0 = *(const unsigned*)(x + (size_t)s0 * D + lane * 2);
            const unsigned v1 = *(const unsigned*)(x + (size_t)s1 * D + lane * 2);
            const unsigned v2 = *(const unsigned*)(x + (size_t)s2 * D + lane * 2);
            const unsigned v3 = *(const unsigned*)(x + (size_t)s3 * D + lane * 2);
            ax = fmaf(c0, bflo(v0), ax); ay = fmaf(c0, bfhi(v0), ay);
            ax = fmaf(c1, bflo(v1), ax); ay = fmaf(c1, bfhi(v1), ay);
            ax = fmaf(c2, bflo(v2), ax); ay = fmaf(c2, bfhi(v2), ay);
            ax = fmaf(c3, bflo(v3), ax); ay = fmaf(c3, bfhi(v3), ay);
        }
        for (; t < cnt; ++t) {
            const int   s = __shfl(mp.x, t, 64);
            const float c = __int_as_float(__shfl(mp.y, t, 64));
            const unsigned v = *(const unsigned*)(x + (size_t)s * D + lane * 2);
            ax = fmaf(c, bflo(v), ax);
            ay = fmaf(c, bfhi(v), ay);
        }
    }
}

__global__ void k_conv2(ConvSide A, ConvSide B) {
    int row = (int)((blockIdx.x * blockDim.x + threadIdx.x) >> 6);
    const int lane = threadIdx.x & 63;
    const ConvSide* S = &A;
    if (row >= A.n) {
        row -= A.n;
        if (row >= B.n) return;
        S = &B;
    }
    const size_t roff = (size_t)row * D + lane * 2;
    float ax = 0.f, ay = 0.f;
    if (S->base) {
        const unsigned b = *(const unsigned*)(S->base + roff);
        ax = bflo(b); ay = bfhi(b);
    }
    accum_list(S->x, S->rs1, S->p1, row, lane, ax, ay);
    if (S->rs2) accum_list(S->x, S->rs2, S->p2, row, lane, ax, ay);
    if (S->outf)  *(float2*)(S->outf  + roff) = make_float2(ax, ay);
    if (S->outf2) *(float2*)(S->outf2 + roff) = make_float2(ax, ay);
    if (S->outb)  *(unsigned*)(S->outb + roff) = (f2bf(ay) << 16) | f2bf(ax);
}

extern "C" void kernel_launch(void* const* d_in, const int* in_sizes, int n_in,
                              void* d_out, int out_size, void* d_ws, size_t ws_size,
                              hipStream_t stream) {
    const float* user_emb = (const float*)d_in[0];
    const float* item_emb = (const float*)d_in[1];
    const float* w_edge   = (const float*)d_in[2];
    const int* ou = (const int*)d_in[3];
    const int* oi = (const int*)d_in[4];
    const int* su = (const int*)d_in[5];
    const int* si = (const int*)d_in[6];
    const int* du = (const int*)d_in[7];
    const int* di = (const int*)d_in[8];
    float* out = (float*)d_out;

    const size_t SZ_U = (size_t)N_USERS * D;
    const size_t SZ_I = (size_t)N_ITEMS * D;

    // output slices: (hu, hi, hu, hi, h1u, h1i)
    float* o0 = out;
    float* o1 = o0 + SZ_U;
    float* o2 = o1 + SZ_I;
    float* o3 = o2 + SZ_U;
    float* o4 = o3 + SZ_I;
    float* o5 = o4 + SZ_U;

    // bf16 intermediates live in the o4/o5 slices (dead until loop-2 iter2):
    ushort* tU0 = (ushort*)o4;  ushort* tU1 = tU0 + SZ_U;
    ushort* tI0 = (ushort*)o5;  ushort* tI1 = tI0 + SZ_I;

    // ---- workspace carve-out ----
    char* ws = (char*)d_ws;
    size_t off = 0;
    auto alloc = [&](size_t bytes) -> void* {
        void* p = ws + off;
        off = (off + bytes + 255) & ~(size_t)255;
        return p;
    };

    size_t degBegin = off;
    int* dOU = (int*)alloc(N_USERS * 4);
    int* dOI = (int*)alloc(N_ITEMS * 4);
    int* dSU = (int*)alloc(N_USERS * 4);
    int* dSI = (int*)alloc(N_ITEMS * 4);
    int* dDU = (int*)alloc(N_USERS * 4);
    int* dDI = (int*)alloc(N_ITEMS * 4);
    size_t degEnd = off;

    int* rOU = (int*)alloc((N_USERS + 1) * 4);
    int* rOI = (int*)alloc((N_ITEMS + 1) * 4);
    int* rSU = (int*)alloc((N_USERS + 1) * 4);
    int* rSI = (int*)alloc((N_ITEMS + 1) * 4);
    int* rDU = (int*)alloc((N_USERS + 1) * 4);
    int* rDI = (int*)alloc((N_ITEMS + 1) * 4);

    int* cOU = (int*)alloc(N_USERS * 4);
    int* cOI = (int*)alloc(N_ITEMS * 4);
    int* cSU = (int*)alloc(N_USERS * 4);
    int* cSI = (int*)alloc(N_ITEMS * 4);
    int* cDU = (int*)alloc(N_USERS * 4);
    int* cDI = (int*)alloc(N_ITEMS * 4);

    int* bsum = (int*)alloc(6 * 256 * 4);

    int2* pOU = (int2*)alloc((size_t)NE * 8);
    int2* pOI = (int2*)alloc((size_t)NE * 8);
    int2* pSU = (int2*)alloc((size_t)NE * 8);
    int2* pSI = (int2*)alloc((size_t)NE * 8);
    int2* pDU = (int2*)alloc((size_t)NE * 8);
    int2* pDI = (int2*)alloc((size_t)NE * 8);

    ushort* ebU = (ushort*)alloc(SZ_U * 2);   // bf16 user_emb (scratch in loop2)
    ushort* ebI = (ushort*)alloc(SZ_I * 2);   // bf16 item_emb (scratch in loop2)
    ushort* fUb = (ushort*)alloc(SZ_U * 2);   // bf16 0.5*h_user_seek_f
    ushort* fIb = (ushort*)alloc(SZ_I * 2);   // bf16 0.5*h_item_seek_f

    // ---- phase 0: zero degree histograms; convert embeddings to bf16 ----
    hipMemsetAsync(ws + degBegin, 0, degEnd - degBegin, stream);
    hipLaunchKernelGGL(k_tobf16, dim3((unsigned)(SZ_U / 4 + 255) / 256), dim3(256), 0, stream,
                       user_emb, ebU, (int)(SZ_U / 4));
    hipLaunchKernelGGL(k_tobf16, dim3((unsigned)(SZ_I / 4 + 255) / 256), dim3(256), 0, stream,
                       item_emb, ebI, (int)(SZ_I / 4));

    // ---- phase 1: degrees ----
    hipLaunchKernelGGL(k_degrees, dim3((NE + 255) / 256), dim3(256), 0, stream,
                       ou, oi, su, si, du, di, dOU, dOI, dSU, dSI, dDU, dDI);

    // ---- phase 2: batched scans ----
    ScanArgs sa;
    sa.deg[0] = dOU; sa.rs[0] = rOU; sa.cur[0] = cOU; sa.n[0] = N_USERS;
    sa.deg[1] = dOI; sa.rs[1] = rOI; sa.cur[1] = cOI; sa.n[1] = N_ITEMS;
    sa.deg[2] = dSU; sa.rs[2] = rSU; sa.cur[2] = cSU; sa.n[2] = N_USERS;
    sa.deg[3] = dSI; sa.rs[3] = rSI; sa.cur[3] = cSI; sa.n[3] = N_ITEMS;
    sa.deg[4] = dDU; sa.rs[4] = rDU; sa.cur[4] = cDU; sa.n[4] = N_USERS;
    sa.deg[5] = dDI; sa.rs[5] = rDI; sa.cur[5] = cDI; sa.n[5] = N_ITEMS;
    sa.bsum = bsum;
    {
        const int nb1 = (N_USERS + 1 + 1023) / 1024;
        hipLaunchKernelGGL(k_scan1, dim3(nb1, 6), dim3(256), 0, stream, sa);
        hipLaunchKernelGGL(k_scan2, dim3(6), dim3(256), 0, stream, bsum);
        const int nb3 = (N_USERS + 1 + 255) / 256;
        hipLaunchKernelGGL(k_scan3, dim3(nb3, 6), dim3(256), 0, stream, sa);
    }

    // ---- phase 3: CSR fill ----
    hipLaunchKernelGGL(k_fill, dim3((NE + 255) / 256), dim3(256), 0, stream,
                       ou, oi, su, si, du, di, w_edge,
                       dOU, dOI, dSU, dSI, dDU, dDI,
                       cOU, cOI, cSU, cSI, cDU, cDI,
                       pOU, pOI, pSU, pSI, pDU, pDI);

    auto mkside = [](const ushort* x, const int* rs1, const int2* p1,
                     const int* rs2, const int2* p2, const ushort* base,
                     float* outf, float* outf2, ushort* outb, int n) {
        ConvSide s; s.x = x; s.rs1 = rs1; s.p1 = p1; s.rs2 = rs2; s.p2 = p2;
        s.base = base; s.outf = outf; s.outf2 = outf2; s.outb = outb; s.n = n;
        return s;
    };
    auto conv2 = [&](const ConvSide& A, const ConvSide& B) {
        const int rows = A.n + B.n;
        dim3 g((unsigned)((rows + 3) / 4)), b(256);   // 4 waves/block, 1 wave/row
        hipLaunchKernelGGL(k_conv2, g, b, 0, stream, A, B);
    };

    // ---- phase 4: loop 1 (3 layers), bf16 intermediates, user+item merged ----
    conv2(mkside(ebI, rOU, pOU, rSU, pSU, nullptr, nullptr, nullptr, tU0, N_USERS),
          mkside(ebU, rOI, pOI, rSI, pSI, nullptr, nullptr, nullptr, tI0, N_ITEMS));
    conv2(mkside(tI0, rOU, pOU, rSU, pSU, nullptr, nullptr, nullptr, tU1, N_USERS),
          mkside(tU0, rOI, pOI, rSI, pSI, nullptr, nullptr, nullptr, tI1, N_ITEMS));
    conv2(mkside(tI1, rOU, pOU, rSU, pSU, nullptr, o0, o2, tU0, N_USERS),
          mkside(tU1, rOI, pOI, rSI, pSI, nullptr, o1, o3, tI0, N_ITEMS));

    // ---- phase 5: constant seek terms from bf16 finals; coefs include the 0.5 ----
    conv2(mkside(tI0, rSU, pSU, nullptr, nullptr, nullptr, nullptr, nullptr, fUb, N_USERS),
          mkside(tU0, rSI, pSI, nullptr, nullptr, nullptr, nullptr, nullptr, fIb, N_ITEMS));

    // ---- phase 6: loop 2 (3 layers), dn graph + constant bf16 base ----
    conv2(mkside(ebI, rDU, pDU, nullptr, nullptr, fUb, nullptr, nullptr, tU1, N_USERS),
          mkside(ebU, rDI, pDI, nullptr, nullptr, fIb, nullptr, nullptr, tI1, N_ITEMS));
    conv2(mkside(tI1, rDU, pDU, nullptr, nullptr, fUb, nullptr, nullptr, ebU, N_USERS),
          mkside(tU1, rDI, pDI, nullptr, nullptr, fIb, nullptr, nullptr, ebI, N_ITEMS));
    conv2(mkside(ebI, rDU, pDU, nullptr, nullptr, fUb, o4, nullptr, nullptr, N_USERS),
          mkside(ebU, rDI, pDI, nullptr, nullptr, fIb, o5, nullptr, nullptr, N_ITEMS));
}

// Round 5
// 1258.736 us; speedup vs baseline: 2.1639x; 1.1165x over previous
//
#include <hip/hip_runtime.h>

#define N_USERS 100000
#define N_ITEMS 30000
#define NE      1000000
#define D       128
#define CHUNK   4096
#define STAGE_B 7680

__device__ __forceinline__ unsigned f2bf(float f) {
    unsigned u = __float_as_uint(f);
    return (u + 0x7fffu + ((u >> 16) & 1u)) >> 16;   // RNE, no NaN expected
}
__device__ __forceinline__ float bflo(unsigned v) { return __uint_as_float(v << 16); }
__device__ __forceinline__ float bfhi(unsigned v) { return __uint_as_float(v & 0xffff0000u); }

// ---------------- degree histograms (all 6 index arrays in one pass) ----------------
__global__ void k_degrees(const int* __restrict__ ou, const int* __restrict__ oi,
                          const int* __restrict__ su, const int* __restrict__ si,
                          const int* __restrict__ du, const int* __restrict__ di,
                          int* dOU, int* dOI, int* dSU, int* dSI, int* dDU, int* dDI) {
    int e = blockIdx.x * blockDim.x + threadIdx.x;
    if (e >= NE) return;
    atomicAdd(&dOU[ou[e]], 1);
    atomicAdd(&dOI[oi[e]], 1);
    atomicAdd(&dSU[su[e]], 1);
    atomicAdd(&dSI[si[e]], 1);
    atomicAdd(&dDU[du[e]], 1);
    atomicAdd(&dDI[di[e]], 1);
}

// ---------------- batched exclusive scans: 6 arrays via blockIdx.y ----------------
struct ScanArgs {
    const int* deg[6];
    int* rs[6];
    int* bcur[6];   // per-bucket cursors (pass-A reservation)
    int* bsum;      // [6*256]
    int n[6];
    int shift[6];
};

__global__ void k_scan1(ScanArgs a) {
    __shared__ int lds[256];
    const int ai = blockIdx.y;
    const int n = a.n[ai];
    const int m = n + 1;
    const int t = threadIdx.x;
    const int idx0 = blockIdx.x * 1024 + t * 4;
    const int* __restrict__ deg = a.deg[ai];
    int* __restrict__ out = a.rs[ai];
    int v[4];
    int s = 0;
#pragma unroll
    for (int j = 0; j < 4; ++j) {
        int i = idx0 + j;
        int x = (i < n) ? deg[i] : 0;
        v[j] = s;
        s += x;
    }
    lds[t] = s;
    __syncthreads();
    int add;
    for (int off = 1; off < 256; off <<= 1) {
        add = (t >= off) ? lds[t - off] : 0;
        __syncthreads();
        lds[t] += add;
        __syncthreads();
    }
    const int incl = lds[t];
    const int excl = incl - s;
#pragma unroll
    for (int j = 0; j < 4; ++j) {
        int i = idx0 + j;
        if (i < m) out[i] = excl + v[j];
    }
    if (t == 255) a.bsum[ai * 256 + blockIdx.x] = incl;
}

__global__ void k_scan2(int* bsum) {
    __shared__ int lds[256];
    const int t = threadIdx.x;
    int* b = bsum + blockIdx.x * 256;
    const int x = b[t];
    lds[t] = x;
    __syncthreads();
    int add;
    for (int off = 1; off < 256; off <<= 1) {
        add = (t >= off) ? lds[t - off] : 0;
        __syncthreads();
        lds[t] += add;
        __syncthreads();
    }
    b[t] = lds[t] - x;   // exclusive
}

__global__ void k_scan3(ScanArgs a) {
    const int ai = blockIdx.y;
    const int n = a.n[ai];
    const int i = blockIdx.x * blockDim.x + threadIdx.x;
    if (i >= n + 1) return;
    int v = a.rs[ai][i] + a.bsum[ai * 256 + (i >> 10)];
    a.rs[ai][i] = v;
    if (i < n && (i & ((1 << a.shift[ai]) - 1)) == 0)
        a.bcur[ai][i >> a.shift[ai]] = v;
}

// ---------------- pass A: bucket-binned scatter with LDS multi-split ----------------
struct FillList {
    const int* dst; const int* srcp; const float* w;
    const int* degD; const int* degS;
    int mode;      // 0: c   1: 0.5*w*c   2: 0.5*c
    int shift;
    int* gcur;     // per-bucket cursors (init = bucket region start)
    int2* tmp;     // binned output (bucket-grouped, row-unsorted)
};
struct FillArgs { FillList l[6]; };

__global__ __launch_bounds__(256) void k_binA(FillArgs fa) {
    const FillList L = fa.l[blockIdx.y];
    __shared__ int2 stg[CHUNK];
    __shared__ unsigned char bkt[CHUNK];
    __shared__ int hist[256], sbase[256], scur[256], gbase[256];
    const int t = threadIdx.x;
    const int e0 = blockIdx.x * CHUNK;
    const int ccnt = min(CHUNK, NE - e0);
    hist[t] = 0;
    __syncthreads();
#pragma unroll
    for (int j = 0; j < CHUNK / 256; ++j) {
        const int e = e0 + j * 256 + t;
        if (e < NE) atomicAdd(&hist[L.dst[e] >> L.shift], 1);
    }
    __syncthreads();
    {   // exclusive scan of hist; reserve global space per bucket
        const int x = hist[t];
        sbase[t] = x;
        __syncthreads();
        for (int o = 1; o < 256; o <<= 1) {
            int add = (t >= o) ? sbase[t - o] : 0;
            __syncthreads();
            sbase[t] += add;
            __syncthreads();
        }
        const int excl = sbase[t] - x;
        __syncthreads();
        sbase[t] = excl;
        scur[t] = excl;
        gbase[t] = (x > 0) ? atomicAdd(&L.gcur[t], x) : 0;
    }
    __syncthreads();
#pragma unroll
    for (int j = 0; j < CHUNK / 256; ++j) {
        const int e = e0 + j * 256 + t;
        if (e < NE) {
            const int d = L.dst[e], s = L.srcp[e];
            float c = rsqrtf((float)L.degD[d]) * rsqrtf((float)L.degS[s]);
            if (L.mode == 1) c *= 0.5f * L.w[e];
            else if (L.mode == 2) c *= 0.5f;
            const int b = d >> L.shift;
            const int p = atomicAdd(&scur[b], 1);
            stg[p] = make_int2(((d & ((1 << L.shift) - 1)) << 17) | s, __float_as_int(c));
            bkt[p] = (unsigned char)b;
        }
    }
    __syncthreads();
    for (int i = t; i < ccnt; i += 256) {
        const int b = bkt[i];
        L.tmp[gbase[b] + (i - sbase[b])] = stg[i];
    }
}

// ---------------- pass B: per-bucket exact row sort, coalesced write ----------------
struct SortArgs {
    const int* rs[6];
    const int2* tmp[6];
    int2* outp[6];
    int shift[6];
    int n[6];
    int bofs[7];   // cumulative bucket-count offsets per list
};

__global__ __launch_bounds__(256) void k_binB(SortArgs a) {
    __shared__ int2 stg[STAGE_B];
    __shared__ int lcur[512];
    int l = 0;
    while ((int)blockIdx.x >= a.bofs[l + 1]) ++l;
    const int b = blockIdx.x - a.bofs[l];
    const int shift = a.shift[l], n = a.n[l];
    const int node0 = b << shift;
    const int node1 = min(node0 + (1 << shift), n);
    const int* __restrict__ rs = a.rs[l];
    const int t = threadIdx.x;
    const int bstart = rs[node0], bend = rs[node1], cnt = bend - bstart;
    for (int k = t; k < node1 - node0; k += 256) lcur[k] = rs[node0 + k] - bstart;
    __syncthreads();
    const int2* __restrict__ tmp = a.tmp[l];
    int2* __restrict__ outp = a.outp[l];
    if (cnt <= STAGE_B) {
        for (int i = t; i < cnt; i += 256) {
            const int2 v = tmp[bstart + i];
            const int dl = ((unsigned)v.x) >> 17;
            const int slot = atomicAdd(&lcur[dl], 1);
            stg[slot] = make_int2(v.x & 0x1FFFF, v.y);
        }
        __syncthreads();
        for (int i = t; i < cnt; i += 256) outp[bstart + i] = stg[i];
    } else {  // statistically unreachable fallback, kept for safety
        for (int i = t; i < cnt; i += 256) {
            const int2 v = tmp[bstart + i];
            const int dl = ((unsigned)v.x) >> 17;
            const int slot = atomicAdd(&lcur[dl], 1);
            outp[bstart + slot] = make_int2(v.x & 0x1FFFF, v.y);
        }
    }
}

// ---------------- f32 -> bf16 convert (4 floats / thread) ----------------
__global__ void k_tobf16(const float* __restrict__ in, ushort* __restrict__ out, int n4) {
    int i = blockIdx.x * blockDim.x + threadIdx.x;
    if (i >= n4) return;
    float4 v = ((const float4*)in)[i];
    ((uint2*)out)[i] = make_uint2((f2bf(v.y) << 16) | f2bf(v.x),
                                  (f2bf(v.w) << 16) | f2bf(v.z));
}

// ---------------- fused dual-side conv ----------------
struct ConvSide {
    const ushort* x;
    const int*  rs1; const int2* p1;
    const int*  rs2; const int2* p2;
    const ushort* base;
    float*  outf; float* outf2;
    ushort* outb;
    int n;
};

__device__ __forceinline__ void accum_list(const ushort* __restrict__ x,
                                           const int* __restrict__ rs,
                                           const int2* __restrict__ p,
                                           int row, int lane,
                                           float& ax, float& ay) {
    const int j0 = rs[row], j1 = rs[row + 1];
    for (int jb = j0; jb < j1; jb += 64) {
        int2 mp = make_int2(0, 0);
        if (jb + lane < j1) mp = p[jb + lane];
        const int cnt = min(64, j1 - jb);
        int t = 0;
        for (; t + 4 <= cnt; t += 4) {
            const int   s0 = __shfl(mp.x, t,     64);
            const int   s1 = __shfl(mp.x, t + 1, 64);
            const int   s2 = __shfl(mp.x, t + 2, 64);
            const int   s3 = __shfl(mp.x, t + 3, 64);
            const float c0 = __int_as_float(__shfl(mp.y, t,     64));
            const float c1 = __int_as_float(__shfl(mp.y, t + 1, 64));
            const float c2 = __int_as_float(__shfl(mp.y, t + 2, 64));
            const float c3 = __int_as_float(__shfl(mp.y, t + 3, 64));
            const unsigned v0 = *(const unsigned*)(x + (size_t)s0 * D + lane * 2);
            const unsigned v1 = *(const unsigned*)(x + (size_t)s1 * D + lane * 2);
            const unsigned v2 = *(const unsigned*)(x + (size_t)s2 * D + lane * 2);
            const unsigned v3 = *(const unsigned*)(x + (size_t)s3 * D + lane * 2);
            ax = fmaf(c0, bflo(v0), ax); ay = fmaf(c0, bfhi(v0), ay);
            ax = fmaf(c1, bflo(v1), ax); ay = fmaf(c1, bfhi(v1), ay);
            ax = fmaf(c2, bflo(v2), ax); ay = fmaf(c2, bfhi(v2), ay);
            ax = fmaf(c3, bflo(v3), ax); ay = fmaf(c3, bfhi(v3), ay);
        }
        for (; t < cnt; ++t) {
            const int   s = __shfl(mp.x, t, 64);
            const float c = __int_as_float(__shfl(mp.y, t, 64));
            const unsigned v = *(const unsigned*)(x + (size_t)s * D + lane * 2);
            ax = fmaf(c, bflo(v), ax);
            ay = fmaf(c, bfhi(v), ay);
        }
    }
}

__global__ void k_conv2(ConvSide A, ConvSide B) {
    int row = (int)((blockIdx.x * blockDim.x + threadIdx.x) >> 6);
    const int lane = threadIdx.x & 63;
    const ConvSide* S = &A;
    if (row >= A.n) {
        row -= A.n;
        if (row >= B.n) return;
        S = &B;
    }
    const size_t roff = (size_t)row * D + lane * 2;
    float ax = 0.f, ay = 0.f;
    if (S->base) {
        const unsigned b = *(const unsigned*)(S->base + roff);
        ax = bflo(b); ay = bfhi(b);
    }
    accum_list(S->x, S->rs1, S->p1, row, lane, ax, ay);
    if (S->rs2) accum_list(S->x, S->rs2, S->p2, row, lane, ax, ay);
    if (S->outf)  *(float2*)(S->outf  + roff) = make_float2(ax, ay);
    if (S->outf2) *(float2*)(S->outf2 + roff) = make_float2(ax, ay);
    if (S->outb)  *(unsigned*)(S->outb + roff) = (f2bf(ay) << 16) | f2bf(ax);
}

extern "C" void kernel_launch(void* const* d_in, const int* in_sizes, int n_in,
                              void* d_out, int out_size, void* d_ws, size_t ws_size,
                              hipStream_t stream) {
    const float* user_emb = (const float*)d_in[0];
    const float* item_emb = (const float*)d_in[1];
    const float* w_edge   = (const float*)d_in[2];
    const int* ou = (const int*)d_in[3];
    const int* oi = (const int*)d_in[4];
    const int* su = (const int*)d_in[5];
    const int* si = (const int*)d_in[6];
    const int* du = (const int*)d_in[7];
    const int* di = (const int*)d_in[8];
    float* out = (float*)d_out;

    const size_t SZ_U = (size_t)N_USERS * D;
    const size_t SZ_I = (size_t)N_ITEMS * D;

    const int SH_U = 9;   // 512 users/bucket  -> 196 buckets
    const int SH_I = 7;   // 128 items/bucket  -> 235 buckets
    const int NB_U = (N_USERS + (1 << SH_U) - 1) >> SH_U;
    const int NB_I = (N_ITEMS + (1 << SH_I) - 1) >> SH_I;

    // output slices: (hu, hi, hu, hi, h1u, h1i)
    float* o0 = out;
    float* o1 = o0 + SZ_U;
    float* o2 = o1 + SZ_I;
    float* o3 = o2 + SZ_U;
    float* o4 = o3 + SZ_I;
    float* o5 = o4 + SZ_U;

    // bf16 intermediates live in the o4/o5 slices (dead until loop-2 iter2):
    ushort* tU0 = (ushort*)o4;  ushort* tU1 = tU0 + SZ_U;
    ushort* tI0 = (ushort*)o5;  ushort* tI1 = tI0 + SZ_I;

    // ---- workspace carve-out (~166 MB) ----
    char* ws = (char*)d_ws;
    size_t off = 0;
    auto alloc = [&](size_t bytes) -> void* {
        void* p = ws + off;
        off = (off + bytes + 255) & ~(size_t)255;
        return p;
    };

    size_t degBegin = off;
    int* dOU = (int*)alloc(N_USERS * 4);
    int* dOI = (int*)alloc(N_ITEMS * 4);
    int* dSU = (int*)alloc(N_USERS * 4);
    int* dSI = (int*)alloc(N_ITEMS * 4);
    int* dDU = (int*)alloc(N_USERS * 4);
    int* dDI = (int*)alloc(N_ITEMS * 4);
    size_t degEnd = off;

    int* rOU = (int*)alloc((N_USERS + 1) * 4);
    int* rOI = (int*)alloc((N_ITEMS + 1) * 4);
    int* rSU = (int*)alloc((N_USERS + 1) * 4);
    int* rSI = (int*)alloc((N_ITEMS + 1) * 4);
    int* rDU = (int*)alloc((N_USERS + 1) * 4);
    int* rDI = (int*)alloc((N_ITEMS + 1) * 4);

    int* bcOU = (int*)alloc(256 * 4);
    int* bcOI = (int*)alloc(256 * 4);
    int* bcSU = (int*)alloc(256 * 4);
    int* bcSI = (int*)alloc(256 * 4);
    int* bcDU = (int*)alloc(256 * 4);
    int* bcDI = (int*)alloc(256 * 4);

    int* bsum = (int*)alloc(6 * 256 * 4);

    int2* pOU = (int2*)alloc((size_t)NE * 8);
    int2* pOI = (int2*)alloc((size_t)NE * 8);
    int2* pSU = (int2*)alloc((size_t)NE * 8);
    int2* pSI = (int2*)alloc((size_t)NE * 8);
    int2* pDU = (int2*)alloc((size_t)NE * 8);
    int2* pDI = (int2*)alloc((size_t)NE * 8);

    int2* qOU = (int2*)alloc((size_t)NE * 8);   // binned (pass-A) staging
    int2* qOI = (int2*)alloc((size_t)NE * 8);
    int2* qSU = (int2*)alloc((size_t)NE * 8);
    int2* qSI = (int2*)alloc((size_t)NE * 8);
    int2* qDU = (int2*)alloc((size_t)NE * 8);
    int2* qDI = (int2*)alloc((size_t)NE * 8);

    ushort* ebU = (ushort*)alloc(SZ_U * 2);
    ushort* ebI = (ushort*)alloc(SZ_I * 2);
    ushort* fUb = (ushort*)alloc(SZ_U * 2);
    ushort* fIb = (ushort*)alloc(SZ_I * 2);

    // ---- phase 0: zero degree histograms; convert embeddings to bf16 ----
    hipMemsetAsync(ws + degBegin, 0, degEnd - degBegin, stream);
    hipLaunchKernelGGL(k_tobf16, dim3((unsigned)(SZ_U / 4 + 255) / 256), dim3(256), 0, stream,
                       user_emb, ebU, (int)(SZ_U / 4));
    hipLaunchKernelGGL(k_tobf16, dim3((unsigned)(SZ_I / 4 + 255) / 256), dim3(256), 0, stream,
                       item_emb, ebI, (int)(SZ_I / 4));

    // ---- phase 1: degrees ----
    hipLaunchKernelGGL(k_degrees, dim3((NE + 255) / 256), dim3(256), 0, stream,
                       ou, oi, su, si, du, di, dOU, dOI, dSU, dSI, dDU, dDI);

    // ---- phase 2: batched scans (row starts + bucket cursors) ----
    ScanArgs sa;
    sa.deg[0] = dOU; sa.rs[0] = rOU; sa.bcur[0] = bcOU; sa.n[0] = N_USERS; sa.shift[0] = SH_U;
    sa.deg[1] = dOI; sa.rs[1] = rOI; sa.bcur[1] = bcOI; sa.n[1] = N_ITEMS; sa.shift[1] = SH_I;
    sa.deg[2] = dSU; sa.rs[2] = rSU; sa.bcur[2] = bcSU; sa.n[2] = N_USERS; sa.shift[2] = SH_U;
    sa.deg[3] = dSI; sa.rs[3] = rSI; sa.bcur[3] = bcSI; sa.n[3] = N_ITEMS; sa.shift[3] = SH_I;
    sa.deg[4] = dDU; sa.rs[4] = rDU; sa.bcur[4] = bcDU; sa.n[4] = N_USERS; sa.shift[4] = SH_U;
    sa.deg[5] = dDI; sa.rs[5] = rDI; sa.bcur[5] = bcDI; sa.n[5] = N_ITEMS; sa.shift[5] = SH_I;
    sa.bsum = bsum;
    {
        const int nb1 = (N_USERS + 1 + 1023) / 1024;
        hipLaunchKernelGGL(k_scan1, dim3(nb1, 6), dim3(256), 0, stream, sa);
        hipLaunchKernelGGL(k_scan2, dim3(6), dim3(256), 0, stream, bsum);
        const int nb3 = (N_USERS + 1 + 255) / 256;
        hipLaunchKernelGGL(k_scan3, dim3(nb3, 6), dim3(256), 0, stream, sa);
    }

    // ---- phase 3: binned CSR build ----
    FillArgs fa;
    fa.l[0] = { ou, oi, nullptr, dOU, dOI, 0, SH_U, bcOU, qOU };
    fa.l[1] = { oi, ou, nullptr, dOI, dOU, 0, SH_I, bcOI, qOI };
    fa.l[2] = { su, si, w_edge,  dSU, dSI, 1, SH_U, bcSU, qSU };
    fa.l[3] = { si, su, nullptr, dSI, dSU, 2, SH_I, bcSI, qSI };
    fa.l[4] = { du, di, nullptr, dDU, dDI, 0, SH_U, bcDU, qDU };
    fa.l[5] = { di, du, nullptr, dDI, dDU, 0, SH_I, bcDI, qDI };
    hipLaunchKernelGGL(k_binA, dim3((NE + CHUNK - 1) / CHUNK, 6), dim3(256), 0, stream, fa);

    SortArgs so;
    so.rs[0] = rOU; so.tmp[0] = qOU; so.outp[0] = pOU; so.shift[0] = SH_U; so.n[0] = N_USERS;
    so.rs[1] = rOI; so.tmp[1] = qOI; so.outp[1] = pOI; so.shift[1] = SH_I; so.n[1] = N_ITEMS;
    so.rs[2] = rSU; so.tmp[2] = qSU; so.outp[2] = pSU; so.shift[2] = SH_U; so.n[2] = N_USERS;
    so.rs[3] = rSI; so.tmp[3] = qSI; so.outp[3] = pSI; so.shift[3] = SH_I; so.n[3] = N_ITEMS;
    so.rs[4] = rDU; so.tmp[4] = qDU; so.outp[4] = pDU; so.shift[4] = SH_U; so.n[4] = N_USERS;
    so.rs[5] = rDI; so.tmp[5] = qDI; so.outp[5] = pDI; so.shift[5] = SH_I; so.n[5] = N_ITEMS;
    {
        int nb[6] = { NB_U, NB_I, NB_U, NB_I, NB_U, NB_I };
        so.bofs[0] = 0;
        for (int i = 0; i < 6; ++i) so.bofs[i + 1] = so.bofs[i] + nb[i];
        hipLaunchKernelGGL(k_binB, dim3(so.bofs[6]), dim3(256), 0, stream, so);
    }

    auto mkside = [](const ushort* x, const int* rs1, const int2* p1,
                     const int* rs2, const int2* p2, const ushort* base,
                     float* outf, float* outf2, ushort* outb, int n) {
        ConvSide s; s.x = x; s.rs1 = rs1; s.p1 = p1; s.rs2 = rs2; s.p2 = p2;
        s.base = base; s.outf = outf; s.outf2 = outf2; s.outb = outb; s.n = n;
        return s;
    };
    auto conv2 = [&](const ConvSide& A, const ConvSide& B) {
        const int rows = A.n + B.n;
        dim3 g((unsigned)((rows + 3) / 4)), b(256);
        hipLaunchKernelGGL(k_conv2, g, b, 0, stream, A, B);
    };

    // ---- phase 4: loop 1 (3 layers), bf16 intermediates, user+item merged ----
    conv2(mkside(ebI, rOU, pOU, rSU, pSU, nullptr, nullptr, nullptr, tU0, N_USERS),
          mkside(ebU, rOI, pOI, rSI, pSI, nullptr, nullptr, nullptr, tI0, N_ITEMS));
    conv2(mkside(tI0, rOU, pOU, rSU, pSU, nullptr, nullptr, nullptr, tU1, N_USERS),
          mkside(tU0, rOI, pOI, rSI, pSI, nullptr, nullptr, nullptr, tI1, N_ITEMS));
    conv2(mkside(tI1, rOU, pOU, rSU, pSU, nullptr, o0, o2, tU0, N_USERS),
          mkside(tU1, rOI, pOI, rSI, pSI, nullptr, o1, o3, tI0, N_ITEMS));

    // ---- phase 5: constant seek terms from bf16 finals; coefs include the 0.5 ----
    conv2(mkside(tI0, rSU, pSU, nullptr, nullptr, nullptr, nullptr, nullptr, fUb, N_USERS),
          mkside(tU0, rSI, pSI, nullptr, nullptr, nullptr, nullptr, nullptr, fIb, N_ITEMS));

    // ---- phase 6: loop 2 (3 layers), dn graph + constant bf16 base ----
    conv2(mkside(ebI, rDU, pDU, nullptr, nullptr, fUb, nullptr, nullptr, tU1, N_USERS),
          mkside(ebU, rDI, pDI, nullptr, nullptr, fIb, nullptr, nullptr, tI1, N_ITEMS));
    conv2(mkside(tI1, rDU, pDU, nullptr, nullptr, fUb, nullptr, nullptr, ebU, N_USERS),
          mkside(tU1, rDI, pDI, nullptr, nullptr, fIb, nullptr, nullptr, ebI, N_ITEMS));
    conv2(mkside(ebI, rDU, pDU, nullptr, nullptr, fUb, o4, nullptr, nullptr, N_USERS),
          mkside(ebU, rDI, pDI, nullptr, nullptr, fIb, o5, nullptr, nullptr, N_ITEMS));
}

// Round 6
// 977.358 us; speedup vs baseline: 2.7869x; 1.2879x over previous
//
#include <hip/hip_runtime.h>

#define N_USERS 100000
#define N_ITEMS 30000
#define NE      1000000
#define D       128
#define CHUNK   4096
#define HCHUNK  8192
#define STAGE_B 7424
#define SH_U    9    // 512 users/bucket  -> 196 buckets
#define SH_I    7    // 128 items/bucket  -> 235 buckets
#define NB_U    ((N_USERS + (1 << SH_U) - 1) >> SH_U)
#define NB_I    ((N_ITEMS + (1 << SH_I) - 1) >> SH_I)

__device__ __forceinline__ unsigned f2bf(float f) {
    unsigned u = __float_as_uint(f);
    return (u + 0x7fffu + ((u >> 16) & 1u)) >> 16;   // RNE, no NaN expected
}
__device__ __forceinline__ float bflo(unsigned v) { return __uint_as_float(v << 16); }
__device__ __forceinline__ float bfhi(unsigned v) { return __uint_as_float(v & 0xffff0000u); }

// ---------------- bucket histograms (LDS-aggregated, tiny global atomics) ----------
struct HistArgs { const int* dst[6]; int shift[6]; int* bh; };

__global__ __launch_bounds__(256) void k_bhist(HistArgs a) {
    __shared__ int h[256];
    const int l = blockIdx.y;
    const int* __restrict__ dst = a.dst[l];
    const int sh = a.shift[l];
    const int t = threadIdx.x;
    h[t] = 0;
    __syncthreads();
    const int e0 = blockIdx.x * HCHUNK;
    const int e1 = min(e0 + HCHUNK, NE);
    for (int e = e0 + t; e < e1; e += 256) atomicAdd(&h[dst[e] >> sh], 1);
    __syncthreads();
    if (h[t]) atomicAdd(&a.bh[l * 256 + t], h[t]);
}

// ---------------- bucket-count scan: bucket starts + pass-A cursors ----------------
__global__ void k_scanB(const int* __restrict__ bh, int* __restrict__ bstart,
                        int* __restrict__ gcur) {
    __shared__ int lds[256];
    const int l = blockIdx.x, t = threadIdx.x;
    const int x = bh[l * 256 + t];
    lds[t] = x;
    __syncthreads();
    for (int o = 1; o < 256; o <<= 1) {
        int add = (t >= o) ? lds[t - o] : 0;
        __syncthreads();
        lds[t] += add;
        __syncthreads();
    }
    const int excl = lds[t] - x;
    bstart[l * 257 + t] = excl;
    gcur[l * 256 + t] = excl;
    if (t == 255) bstart[l * 257 + 256] = lds[t];
}

// ---------------- pass A: bucket-binned scatter (no coefficients yet) --------------
struct BinList { const int* dst; const int* srcp; const float* w; int shift; int* gcur; int2* tmp; };
struct BinArgs { BinList l[6]; };

__global__ __launch_bounds__(256) void k_binA(BinArgs ba) {
    const BinList L = ba.l[blockIdx.y];
    __shared__ int2 stg[CHUNK];
    __shared__ unsigned char bkt[CHUNK];
    __shared__ int hist[256], sbase[256], scur[256], gbase[256];
    const int t = threadIdx.x;
    const int e0 = blockIdx.x * CHUNK;
    const int ccnt = min(CHUNK, NE - e0);
    hist[t] = 0;
    __syncthreads();
#pragma unroll
    for (int j = 0; j < CHUNK / 256; ++j) {
        const int e = e0 + j * 256 + t;
        if (e < NE) atomicAdd(&hist[L.dst[e] >> L.shift], 1);
    }
    __syncthreads();
    {
        const int x = hist[t];
        sbase[t] = x;
        __syncthreads();
        for (int o = 1; o < 256; o <<= 1) {
            int add = (t >= o) ? sbase[t - o] : 0;
            __syncthreads();
            sbase[t] += add;
            __syncthreads();
        }
        const int excl = sbase[t] - x;
        __syncthreads();
        sbase[t] = excl;
        scur[t] = excl;
        gbase[t] = (x > 0) ? atomicAdd(&L.gcur[t], x) : 0;
    }
    __syncthreads();
#pragma unroll
    for (int j = 0; j < CHUNK / 256; ++j) {
        const int e = e0 + j * 256 + t;
        if (e < NE) {
            const int d = L.dst[e], s = L.srcp[e];
            const int b = d >> L.shift;
            const int p = atomicAdd(&scur[b], 1);
            stg[p] = make_int2(((d & ((1 << L.shift) - 1)) << 17) | s,
                               L.w ? __float_as_int(L.w[e]) : 0);
            bkt[p] = (unsigned char)b;
        }
    }
    __syncthreads();
    for (int i = t; i < ccnt; i += 256) {
        const int b = bkt[i];
        L.tmp[gbase[b] + (i - sbase[b])] = stg[i];
    }
}

// ---------------- per-bucket degree count + row starts (coalesced writes) ----------
struct DegArgs {
    const int2* tmp[6];
    const int* bstart;       // [6*257]
    int* rs[6];
    float* rdeg[6];
    int shift[6]; int n[6]; int bofs[7];
};

__global__ __launch_bounds__(256) void k_bdeg(DegArgs a) {
    __shared__ int cnt[512];
    __shared__ int lds[256];
    int l = 0;
    while ((int)blockIdx.x >= a.bofs[l + 1]) ++l;
    const int b = blockIdx.x - a.bofs[l];
    const int sh = a.shift[l], n = a.n[l];
    const int node0 = b << sh;
    const int node1 = min(node0 + (1 << sh), n);
    const int nn = node1 - node0;
    const int bs = a.bstart[l * 257 + b], be = a.bstart[l * 257 + b + 1];
    const int t = threadIdx.x;
    cnt[t] = 0; cnt[t + 256] = 0;
    __syncthreads();
    const int2* __restrict__ tmp = a.tmp[l];
    for (int i = bs + t; i < be; i += 256) atomicAdd(&cnt[((unsigned)tmp[i].x) >> 17], 1);
    __syncthreads();
    const int c0 = cnt[2 * t], c1 = cnt[2 * t + 1];
    lds[t] = c0 + c1;
    __syncthreads();
    for (int o = 1; o < 256; o <<= 1) {
        int add = (t >= o) ? lds[t - o] : 0;
        __syncthreads();
        lds[t] += add;
        __syncthreads();
    }
    const int ep = lds[t] - (c0 + c1);   // exclusive prefix at element 2t
    int* __restrict__ rs = a.rs[l];
    float* __restrict__ rd = a.rdeg[l];
    if (2 * t < nn) {
        rs[node0 + 2 * t] = bs + ep;
        rd[node0 + 2 * t] = rsqrtf((float)max(c0, 1));
    }
    if (2 * t + 1 < nn) {
        rs[node0 + 2 * t + 1] = bs + ep + c0;
        rd[node0 + 2 * t + 1] = rsqrtf((float)max(c1, 1));
    }
    if (t == 0) rs[node1] = be;
}

// ---------------- pass B: coefficient compute + exact row sort, coalesced ----------
struct SortArgs {
    const int2* tmp[6]; int2* outp[6];
    const int* rs[6];
    const float* rdD[6]; const float* rdS[6];
    const int* bstart;
    int shift[6]; int n[6]; int mode[6];   // mode 0: c  1: 0.5*w*c  2: 0.5*c
    int bofs[7];
};

__global__ __launch_bounds__(256) void k_binB(SortArgs a) {
    __shared__ int2 stg[STAGE_B];
    __shared__ int lcur[512];
    __shared__ float rdl[512];
    int l = 0;
    while ((int)blockIdx.x >= a.bofs[l + 1]) ++l;
    const int b = blockIdx.x - a.bofs[l];
    const int sh = a.shift[l], n = a.n[l], mode = a.mode[l];
    const int node0 = b << sh;
    const int node1 = min(node0 + (1 << sh), n);
    const int nn = node1 - node0;
    const int bs = a.bstart[l * 257 + b], be = a.bstart[l * 257 + b + 1], cnt = be - bs;
    const int t = threadIdx.x;
    const int* __restrict__ rs = a.rs[l];
    const float* __restrict__ rdD = a.rdD[l];
    for (int k = t; k < nn; k += 256) {
        lcur[k] = rs[node0 + k] - bs;
        rdl[k] = rdD[node0 + k];
    }
    __syncthreads();
    const int2* __restrict__ tmp = a.tmp[l];
    int2* __restrict__ outp = a.outp[l];
    const float* __restrict__ rdS = a.rdS[l];
    if (cnt <= STAGE_B) {
        for (int i = bs + t; i < be; i += 256) {
            const int2 v = tmp[i];
            const int dl = ((unsigned)v.x) >> 17, src = v.x & 0x1FFFF;
            float c = rdl[dl] * rdS[src];
            if (mode == 1) c *= 0.5f * __int_as_float(v.y);
            else if (mode == 2) c *= 0.5f;
            const int slot = atomicAdd(&lcur[dl], 1);
            stg[slot] = make_int2(src, __float_as_int(c));
        }
        __syncthreads();
        for (int i = t; i < cnt; i += 256) outp[bs + i] = stg[i];
    } else {  // statistically unreachable fallback
        for (int i = bs + t; i < be; i += 256) {
            const int2 v = tmp[i];
            const int dl = ((unsigned)v.x) >> 17, src = v.x & 0x1FFFF;
            float c = rdl[dl] * rdS[src];
            if (mode == 1) c *= 0.5f * __int_as_float(v.y);
            else if (mode == 2) c *= 0.5f;
            const int slot = atomicAdd(&lcur[dl], 1);
            outp[bs + slot] = make_int2(src, __float_as_int(c));
        }
    }
}

// ---------------- f32 -> bf16 convert (4 floats / thread) ----------------
__global__ void k_tobf16(const float* __restrict__ in, ushort* __restrict__ out, int n4) {
    int i = blockIdx.x * blockDim.x + threadIdx.x;
    if (i >= n4) return;
    float4 v = ((const float4*)in)[i];
    ((uint2*)out)[i] = make_uint2((f2bf(v.y) << 16) | f2bf(v.x),
                                  (f2bf(v.w) << 16) | f2bf(v.z));
}

// ---------------- fused dual-side conv (unroll 8) ----------------
struct ConvSide {
    const ushort* x;
    const int*  rs1; const int2* p1;
    const int*  rs2; const int2* p2;
    const ushort* base;
    float*  outf; float* outf2;
    ushort* outb;
    int n;
};

__device__ __forceinline__ void accum_list(const ushort* __restrict__ x,
                                           const int* __restrict__ rs,
                                           const int2* __restrict__ p,
                                           int row, int lane,
                                           float& ax, float& ay) {
    const int j0 = rs[row], j1 = rs[row + 1];
    for (int jb = j0; jb < j1; jb += 64) {
        int2 mp = make_int2(0, 0);
        if (jb + lane < j1) mp = p[jb + lane];
        const int cnt = min(64, j1 - jb);
        int t = 0;
        for (; t + 8 <= cnt; t += 8) {
            unsigned v[8]; float c[8];
#pragma unroll
            for (int k = 0; k < 8; ++k) {
                const int s = __shfl(mp.x, t + k, 64);
                c[k] = __int_as_float(__shfl(mp.y, t + k, 64));
                v[k] = *(const unsigned*)(x + (size_t)s * D + lane * 2);
            }
#pragma unroll
            for (int k = 0; k < 8; ++k) {
                ax = fmaf(c[k], bflo(v[k]), ax);
                ay = fmaf(c[k], bfhi(v[k]), ay);
            }
        }
        if (t + 4 <= cnt) {
            unsigned v[4]; float c[4];
#pragma unroll
            for (int k = 0; k < 4; ++k) {
                const int s = __shfl(mp.x, t + k, 64);
                c[k] = __int_as_float(__shfl(mp.y, t + k, 64));
                v[k] = *(const unsigned*)(x + (size_t)s * D + lane * 2);
            }
#pragma unroll
            for (int k = 0; k < 4; ++k) {
                ax = fmaf(c[k], bflo(v[k]), ax);
                ay = fmaf(c[k], bfhi(v[k]), ay);
            }
            t += 4;
        }
        for (; t < cnt; ++t) {
            const int s = __shfl(mp.x, t, 64);
            const float c = __int_as_float(__shfl(mp.y, t, 64));
            const unsigned v = *(const unsigned*)(x + (size_t)s * D + lane * 2);
            ax = fmaf(c, bflo(v), ax);
            ay = fmaf(c, bfhi(v), ay);
        }
    }
}

__global__ void k_conv2(ConvSide A, ConvSide B) {
    int row = (int)((blockIdx.x * blockDim.x + threadIdx.x) >> 6);
    const int lane = threadIdx.x & 63;
    const ConvSide* S = &A;
    if (row >= A.n) {
        row -= A.n;
        if (row >= B.n) return;
        S = &B;
    }
    const size_t roff = (size_t)row * D + lane * 2;
    float ax = 0.f, ay = 0.f;
    if (S->base) {
        const unsigned b = *(const unsigned*)(S->base + roff);
        ax = bflo(b); ay = bfhi(b);
    }
    accum_list(S->x, S->rs1, S->p1, row, lane, ax, ay);
    if (S->rs2) accum_list(S->x, S->rs2, S->p2, row, lane, ax, ay);
    if (S->outf)  *(float2*)(S->outf  + roff) = make_float2(ax, ay);
    if (S->outf2) *(float2*)(S->outf2 + roff) = make_float2(ax, ay);
    if (S->outb)  *(unsigned*)(S->outb + roff) = (f2bf(ay) << 16) | f2bf(ax);
}

extern "C" void kernel_launch(void* const* d_in, const int* in_sizes, int n_in,
                              void* d_out, int out_size, void* d_ws, size_t ws_size,
                              hipStream_t stream) {
    const float* user_emb = (const float*)d_in[0];
    const float* item_emb = (const float*)d_in[1];
    const float* w_edge   = (const float*)d_in[2];
    const int* ou = (const int*)d_in[3];
    const int* oi = (const int*)d_in[4];
    const int* su = (const int*)d_in[5];
    const int* si = (const int*)d_in[6];
    const int* du = (const int*)d_in[7];
    const int* di = (const int*)d_in[8];
    float* out = (float*)d_out;

    const size_t SZ_U = (size_t)N_USERS * D;
    const size_t SZ_I = (size_t)N_ITEMS * D;

    // output slices: (hu, hi, hu, hi, h1u, h1i)
    float* o0 = out;
    float* o1 = o0 + SZ_U;
    float* o2 = o1 + SZ_I;
    float* o3 = o2 + SZ_U;
    float* o4 = o3 + SZ_I;
    float* o5 = o4 + SZ_U;

    // bf16 intermediates live in the o4/o5 slices (dead until loop-2 iter2):
    ushort* tU0 = (ushort*)o4;  ushort* tU1 = tU0 + SZ_U;
    ushort* tI0 = (ushort*)o5;  ushort* tI1 = tI0 + SZ_I;

    // ---- workspace carve-out ----
    char* ws = (char*)d_ws;
    size_t off = 0;
    auto alloc = [&](size_t bytes) -> void* {
        void* p = ws + off;
        off = (off + bytes + 255) & ~(size_t)255;
        return p;
    };

    int* rOU = (int*)alloc((N_USERS + 1) * 4);
    int* rOI = (int*)alloc((N_ITEMS + 1) * 4);
    int* rSU = (int*)alloc((N_USERS + 1) * 4);
    int* rSI = (int*)alloc((N_ITEMS + 1) * 4);
    int* rDU = (int*)alloc((N_USERS + 1) * 4);
    int* rDI = (int*)alloc((N_ITEMS + 1) * 4);

    float* rdOU = (float*)alloc(N_USERS * 4);
    float* rdOI = (float*)alloc(N_ITEMS * 4);
    float* rdSU = (float*)alloc(N_USERS * 4);
    float* rdSI = (float*)alloc(N_ITEMS * 4);
    float* rdDU = (float*)alloc(N_USERS * 4);
    float* rdDI = (float*)alloc(N_ITEMS * 4);

    size_t bhBegin = off;
    int* bh     = (int*)alloc(6 * 256 * 4);
    size_t bhEnd = off;
    int* bstart = (int*)alloc(6 * 257 * 4);
    int* gcur   = (int*)alloc(6 * 256 * 4);

    int2* pOU = (int2*)alloc((size_t)NE * 8);
    int2* pOI = (int2*)alloc((size_t)NE * 8);
    int2* pSU = (int2*)alloc((size_t)NE * 8);
    int2* pSI = (int2*)alloc((size_t)NE * 8);
    int2* pDU = (int2*)alloc((size_t)NE * 8);
    int2* pDI = (int2*)alloc((size_t)NE * 8);

    int2* qOU = (int2*)alloc((size_t)NE * 8);   // binned (pass-A) staging
    int2* qOI = (int2*)alloc((size_t)NE * 8);
    int2* qSU = (int2*)alloc((size_t)NE * 8);
    int2* qSI = (int2*)alloc((size_t)NE * 8);
    int2* qDU = (int2*)alloc((size_t)NE * 8);
    int2* qDI = (int2*)alloc((size_t)NE * 8);

    ushort* ebU = (ushort*)alloc(SZ_U * 2);
    ushort* ebI = (ushort*)alloc(SZ_I * 2);
    ushort* fUb = (ushort*)alloc(SZ_U * 2);
    ushort* fIb = (ushort*)alloc(SZ_I * 2);

    // ---- phase 0: zero bucket hist; convert embeddings to bf16 ----
    hipMemsetAsync(ws + bhBegin, 0, bhEnd - bhBegin, stream);
    hipLaunchKernelGGL(k_tobf16, dim3((unsigned)(SZ_U / 4 + 255) / 256), dim3(256), 0, stream,
                       user_emb, ebU, (int)(SZ_U / 4));
    hipLaunchKernelGGL(k_tobf16, dim3((unsigned)(SZ_I / 4 + 255) / 256), dim3(256), 0, stream,
                       item_emb, ebI, (int)(SZ_I / 4));

    // ---- phase 1: bucket histograms + bucket scan ----
    HistArgs ha;
    ha.dst[0] = ou; ha.shift[0] = SH_U;
    ha.dst[1] = oi; ha.shift[1] = SH_I;
    ha.dst[2] = su; ha.shift[2] = SH_U;
    ha.dst[3] = si; ha.shift[3] = SH_I;
    ha.dst[4] = du; ha.shift[4] = SH_U;
    ha.dst[5] = di; ha.shift[5] = SH_I;
    ha.bh = bh;
    hipLaunchKernelGGL(k_bhist, dim3((NE + HCHUNK - 1) / HCHUNK, 6), dim3(256), 0, stream, ha);
    hipLaunchKernelGGL(k_scanB, dim3(6), dim3(256), 0, stream, bh, bstart, gcur);

    // ---- phase 2: pass A (bin by destination bucket) ----
    BinArgs ba;
    ba.l[0] = { ou, oi, nullptr, SH_U, gcur + 0 * 256, qOU };
    ba.l[1] = { oi, ou, nullptr, SH_I, gcur + 1 * 256, qOI };
    ba.l[2] = { su, si, w_edge,  SH_U, gcur + 2 * 256, qSU };
    ba.l[3] = { si, su, nullptr, SH_I, gcur + 3 * 256, qSI };
    ba.l[4] = { du, di, nullptr, SH_U, gcur + 4 * 256, qDU };
    ba.l[5] = { di, du, nullptr, SH_I, gcur + 5 * 256, qDI };
    hipLaunchKernelGGL(k_binA, dim3((NE + CHUNK - 1) / CHUNK, 6), dim3(256), 0, stream, ba);

    int bofs[7];
    {
        int nb[6] = { NB_U, NB_I, NB_U, NB_I, NB_U, NB_I };
        bofs[0] = 0;
        for (int i = 0; i < 6; ++i) bofs[i + 1] = bofs[i] + nb[i];
    }

    // ---- phase 3: per-bucket degrees + row starts ----
    DegArgs da;
    da.tmp[0] = qOU; da.rs[0] = rOU; da.rdeg[0] = rdOU; da.shift[0] = SH_U; da.n[0] = N_USERS;
    da.tmp[1] = qOI; da.rs[1] = rOI; da.rdeg[1] = rdOI; da.shift[1] = SH_I; da.n[1] = N_ITEMS;
    da.tmp[2] = qSU; da.rs[2] = rSU; da.rdeg[2] = rdSU; da.shift[2] = SH_U; da.n[2] = N_USERS;
    da.tmp[3] = qSI; da.rs[3] = rSI; da.rdeg[3] = rdSI; da.shift[3] = SH_I; da.n[3] = N_ITEMS;
    da.tmp[4] = qDU; da.rs[4] = rDU; da.rdeg[4] = rdDU; da.shift[4] = SH_U; da.n[4] = N_USERS;
    da.tmp[5] = qDI; da.rs[5] = rDI; da.rdeg[5] = rdDI; da.shift[5] = SH_I; da.n[5] = N_ITEMS;
    da.bstart = bstart;
    for (int i = 0; i < 7; ++i) da.bofs[i] = bofs[i];
    hipLaunchKernelGGL(k_bdeg, dim3(bofs[6]), dim3(256), 0, stream, da);

    // ---- phase 4: pass B (coefficients + exact row sort) ----
    SortArgs so;
    so.tmp[0] = qOU; so.outp[0] = pOU; so.rs[0] = rOU; so.rdD[0] = rdOU; so.rdS[0] = rdOI;
    so.shift[0] = SH_U; so.n[0] = N_USERS; so.mode[0] = 0;
    so.tmp[1] = qOI; so.outp[1] = pOI; so.rs[1] = rOI; so.rdD[1] = rdOI; so.rdS[1] = rdOU;
    so.shift[1] = SH_I; so.n[1] = N_ITEMS; so.mode[1] = 0;
    so.tmp[2] = qSU; so.outp[2] = pSU; so.rs[2] = rSU; so.rdD[2] = rdSU; so.rdS[2] = rdSI;
    so.shift[2] = SH_U; so.n[2] = N_USERS; so.mode[2] = 1;
    so.tmp[3] = qSI; so.outp[3] = pSI; so.rs[3] = rSI; so.rdD[3] = rdSI; so.rdS[3] = rdSU;
    so.shift[3] = SH_I; so.n[3] = N_ITEMS; so.mode[3] = 2;
    so.tmp[4] = qDU; so.outp[4] = pDU; so.rs[4] = rDU; so.rdD[4] = rdDU; so.rdS[4] = rdDI;
    so.shift[4] = SH_U; so.n[4] = N_USERS; so.mode[4] = 0;
    so.tmp[5] = qDI; so.outp[5] = pDI; so.rs[5] = rDI; so.rdD[5] = rdDI; so.rdS[5] = rdDU;
    so.shift[5] = SH_I; so.n[5] = N_ITEMS; so.mode[5] = 0;
    so.bstart = bstart;
    for (int i = 0; i < 7; ++i) so.bofs[i] = bofs[i];
    hipLaunchKernelGGL(k_binB, dim3(bofs[6]), dim3(256), 0, stream, so);

    auto mkside = [](const ushort* x, const int* rs1, const int2* p1,
                     const int* rs2, const int2* p2, const ushort* base,
                     float* outf, float* outf2, ushort* outb, int n) {
        ConvSide s; s.x = x; s.rs1 = rs1; s.p1 = p1; s.rs2 = rs2; s.p2 = p2;
        s.base = base; s.outf = outf; s.outf2 = outf2; s.outb = outb; s.n = n;
        return s;
    };
    auto conv2 = [&](const ConvSide& A, const ConvSide& B) {
        const int rows = A.n + B.n;
        dim3 g((unsigned)((rows + 3) / 4)), b(256);
        hipLaunchKernelGGL(k_conv2, g, b, 0, stream, A, B);
    };

    // ---- phase 5: loop 1 (3 layers), bf16 intermediates, user+item merged ----
    conv2(mkside(ebI, rOU, pOU, rSU, pSU, nullptr, nullptr, nullptr, tU0, N_USERS),
          mkside(ebU, rOI, pOI, rSI, pSI, nullptr, nullptr, nullptr, tI0, N_ITEMS));
    conv2(mkside(tI0, rOU, pOU, rSU, pSU, nullptr, nullptr, nullptr, tU1, N_USERS),
          mkside(tU0, rOI, pOI, rSI, pSI, nullptr, nullptr, nullptr, tI1, N_ITEMS));
    conv2(mkside(tI1, rOU, pOU, rSU, pSU, nullptr, o0, o2, tU0, N_USERS),
          mkside(tU1, rOI, pOI, rSI, pSI, nullptr, o1, o3, tI0, N_ITEMS));

    // ---- phase 6: constant seek terms from bf16 finals; coefs include the 0.5 ----
    conv2(mkside(tI0, rSU, pSU, nullptr, nullptr, nullptr, nullptr, nullptr, fUb, N_USERS),
          mkside(tU0, rSI, pSI, nullptr, nullptr, nullptr, nullptr, nullptr, fIb, N_ITEMS));

    // ---- phase 7: loop 2 (3 layers), dn graph + constant bf16 base ----
    conv2(mkside(ebI, rDU, pDU, nullptr, nullptr, fUb, nullptr, nullptr, tU1, N_USERS),
          mkside(ebU, rDI, pDI, nullptr, nullptr, fIb, nullptr, nullptr, tI1, N_ITEMS));
    conv2(mkside(tI1, rDU, pDU, nullptr, nullptr, fUb, nullptr, nullptr, ebU, N_USERS),
          mkside(tU1, rDI, pDI, nullptr, nullptr, fIb, nullptr, nullptr, ebI, N_ITEMS));
    conv2(mkside(ebI, rDU, pDU, nullptr, nullptr, fUb, o4, nullptr, nullptr, N_USERS),
          mkside(ebU, rDI, pDI, nullptr, nullptr, fIb, o5, nullptr, nullptr, N_ITEMS));
}